// Round 5
// baseline (528.154 us; speedup 1.0000x reference)
//
#include <hip/hip_runtime.h>

// EtaGNN: 2x SAGE-conv (mean agg) + factorized MLP link predictor.
// Strategy: project-then-aggregate (linearity of mean), CSR gather (no f32 atomics),
// factorized query head (A[u]+B[v]+t*wt).
// R1: register-light dual_gemm (R0 spilled at 256 VGPR).
// R2: X tile in LDS, agg/query 16-lane float4 groups.
// R3: GEMM v4 - W via prefetched global float4, 64 rows/block; Wm1 pre-split.
// R4: CSR fill was 51us with 52MB write-allocate traffic (random 4B scatter).
//     Replaced by 2-pass binned fill: bucket(dst>>7) scatter into 391 sequential
//     streams (packed (local<<16)|src), then per-bucket LDS-cursor fill.

constexpr int NN = 50000;   // nodes
constexpr int NE = 800000;  // edges
constexpr int NQ = 400000;  // queries
constexpr int NBUCKET = (NN + 127) >> 7;  // 391 buckets of 128 nodes

// ---------------- CSR build ----------------
__global__ void count_kernel(const int* __restrict__ dst, int* __restrict__ cnt) {
    int e = blockIdx.x * 256 + threadIdx.x;
    if (e < NE) atomicAdd(&cnt[dst[e]], 1);
}

constexpr int SCHUNK = 1024;
constexpr int SBLK = (NN + SCHUNK - 1) / SCHUNK;  // 49 blocks

__global__ void scan_sum_kernel(const int* __restrict__ cnt, int* __restrict__ bsum) {
    __shared__ int sd[256];
    int t = threadIdx.x;
    int base = blockIdx.x * SCHUNK;
    int s = 0;
#pragma unroll
    for (int j = 0; j < 4; ++j) {
        int i = base + t + j * 256;
        if (i < NN) s += cnt[i];
    }
    sd[t] = s; __syncthreads();
    for (int off = 128; off > 0; off >>= 1) {
        if (t < off) sd[t] += sd[t + off];
        __syncthreads();
    }
    if (t == 0) bsum[blockIdx.x] = sd[0];
}

__global__ void scan_block_kernel(int* bsum) {  // 1 wave, exclusive scan in place
    int t = threadIdx.x;
    int orig = (t < SBLK) ? bsum[t] : 0;
    int v = orig;
#pragma unroll
    for (int off = 1; off < 64; off <<= 1) {
        int w = __shfl_up(v, off);
        if (t >= off) v += w;
    }
    if (t < SBLK) bsum[t] = v - orig;
}

__global__ void scan_write_kernel(const int* __restrict__ bsum, int* __restrict__ row_start,
                                  const int* __restrict__ cnt, int* __restrict__ bucket_cursor) {
    __shared__ int wsum[4];
    int t = threadIdx.x, lane = t & 63, wid = t >> 6;
    int base = blockIdx.x * SCHUNK;
    int v[4]; int s = 0;
#pragma unroll
    for (int j = 0; j < 4; ++j) {
        int i = base + t * 4 + j;
        v[j] = (i < NN) ? cnt[i] : 0;
        s += v[j];
    }
    int orig = s;
#pragma unroll
    for (int off = 1; off < 64; off <<= 1) {
        int w = __shfl_up(s, off);
        if (lane >= off) s += w;
    }
    if (lane == 63) wsum[wid] = s;
    __syncthreads();
    int woff = 0;
    for (int w = 0; w < wid; ++w) woff += wsum[w];
    int excl = bsum[blockIdx.x] + woff + (s - orig);
#pragma unroll
    for (int j = 0; j < 4; ++j) {
        int i = base + t * 4 + j;
        if (i <= NN) {
            row_start[i] = excl;
            if (i < NN && (i & 127) == 0) bucket_cursor[i >> 7] = excl;
            excl += (i < NN) ? v[j] : 0;
        }
    }
}

// scatter edges into bucket-ordered tmp: 391 sequential write streams
__global__ void bin_scatter_kernel(const int* __restrict__ src, const int* __restrict__ dst,
                                   int* __restrict__ bucket_cursor, unsigned* __restrict__ tmp) {
    int e = blockIdx.x * 256 + threadIdx.x;
    if (e < NE) {
        int d = dst[e];
        int p = atomicAdd(&bucket_cursor[d >> 7], 1);
        tmp[p] = ((unsigned)(d & 127) << 16) | (unsigned)src[e];
    }
}

// per-bucket: LDS cursors from row_start, fill csr_src within contiguous window
__global__ __launch_bounds__(256) void csr_fill_kernel(const int* __restrict__ row_start,
                                                       const unsigned* __restrict__ tmp,
                                                       int* __restrict__ csr_src) {
    __shared__ int cur[128];
    int b = blockIdx.x;
    int node_base = b << 7;
    int n_nodes = NN - node_base; if (n_nodes > 128) n_nodes = 128;
    int t = threadIdx.x;
    if (t < n_nodes) cur[t] = row_start[node_base + t];
    __syncthreads();
    int bstart = row_start[node_base];
    int bend = row_start[node_base + n_nodes];
    for (int e = bstart + t; e < bend; e += 256) {
        unsigned pk = tmp[e];
        int p = atomicAdd(&cur[pk >> 16], 1);
        csr_src[p] = (int)(pk & 0xFFFFu);
    }
}

// ---------------- Wm1 split: WmA[64][64], WmB[64][64], wt[64] ----------------
__global__ void prep_wm1_kernel(const float* __restrict__ Wm1, float* __restrict__ WmA,
                                float* __restrict__ WmB, float* __restrict__ wt) {
    int t = blockIdx.x * 256 + threadIdx.x;
    if (t < 64 * 64) {
        int c = t >> 6, k = t & 63;
        WmA[t] = Wm1[c * 129 + k];
        WmB[t] = Wm1[c * 129 + 64 + k];
    }
    if (t < 64) wt[t] = Wm1[t * 129 + 128];
}

// ---------------- dual GEMM: outA = in @ Wa.T, outB = in @ Wb.T  (Cout=64, row stride K) ----
// 256 threads = 4 waves; wave owns 16 rows, lane owns 1 col of each output.
// X tile in LDS (uniform broadcast b128 reads); W streamed from global per-thread
// (own row, L1/L2-resident) with 1-step register prefetch. One barrier total.
template <int K>
__global__ __launch_bounds__(256, 4) void dual_gemm_kernel(
    const float* __restrict__ in,
    const float* __restrict__ Wa, const float* __restrict__ Wb,
    float* __restrict__ outA, float* __restrict__ outB) {
    __shared__ float X[64][K];
    int t = threadIdx.x;
    int c = t & 63, g = t >> 6;
    int rbase = blockIdx.x * 64;
    constexpr int KV = K / 4;
    {
        const float4* in4 = (const float4*)in;
        float4* X4 = (float4*)&X[0][0];
        for (int idx = t; idx < 64 * KV; idx += 256) {
            int r = idx / KV, kv = idx - r * KV;
            int gr = rbase + r; if (gr >= NN) gr = NN - 1;  // clamp; stores guarded
            X4[idx] = in4[(size_t)gr * KV + kv];
        }
    }
    float accA[16], accB[16];
#pragma unroll
    for (int j = 0; j < 16; ++j) { accA[j] = 0.f; accB[j] = 0.f; }
    const float* wap = Wa + (size_t)c * K;
    const float* wbp = Wb + (size_t)c * K;
    float4 wa = *(const float4*)wap;
    float4 wb = *(const float4*)wbp;
    __syncthreads();
#pragma unroll 2
    for (int k2 = 0; k2 < K; k2 += 4) {
        float4 wan = wa, wbn = wb;
        if (k2 + 4 < K) {
            wan = *(const float4*)(wap + k2 + 4);
            wbn = *(const float4*)(wbp + k2 + 4);
        }
#pragma unroll
        for (int j = 0; j < 16; ++j) {
            float4 xv = *reinterpret_cast<const float4*>(&X[g * 16 + j][k2]);
            accA[j] = fmaf(xv.x, wa.x, accA[j]);
            accB[j] = fmaf(xv.x, wb.x, accB[j]);
            accA[j] = fmaf(xv.y, wa.y, accA[j]);
            accB[j] = fmaf(xv.y, wb.y, accB[j]);
            accA[j] = fmaf(xv.z, wa.z, accA[j]);
            accB[j] = fmaf(xv.z, wb.z, accB[j]);
            accA[j] = fmaf(xv.w, wa.w, accA[j]);
            accB[j] = fmaf(xv.w, wb.w, accB[j]);
        }
        wa = wan; wb = wbn;
    }
#pragma unroll
    for (int j = 0; j < 16; ++j) {
        int gr = rbase + g * 16 + j;
        if (gr < NN) {
            outA[(size_t)gr * 64 + c] = accA[j];
            outB[(size_t)gr * 64 + c] = accB[j];
        }
    }
}

// ---------------- aggregation: out = relu(sum(p[src])/max(deg,1) + bias + selfp) ----------------
// 16 lanes per node (float4/lane), 4 nodes per wave, 4-deep gather MLP.
__global__ __launch_bounds__(256) void agg_kernel(
    const float* __restrict__ p, const float* __restrict__ selfp,
    const float* __restrict__ bias, const int* __restrict__ row_start,
    const int* __restrict__ csr_src, float* __restrict__ out) {
    int node = blockIdx.x * 16 + (threadIdx.x >> 4);
    int sub = threadIdx.x & 15;
    if (node >= NN) return;
    const float4* p4 = (const float4*)p;
    int s0 = row_start[node], s1 = row_start[node + 1];
    float4 acc = make_float4(0.f, 0.f, 0.f, 0.f);
    int e = s0;
    for (; e + 4 <= s1; e += 4) {
        int i0 = csr_src[e + 0], i1 = csr_src[e + 1];
        int i2 = csr_src[e + 2], i3 = csr_src[e + 3];
        float4 a = p4[(size_t)i0 * 16 + sub];
        float4 b = p4[(size_t)i1 * 16 + sub];
        float4 cc = p4[(size_t)i2 * 16 + sub];
        float4 d = p4[(size_t)i3 * 16 + sub];
        acc.x += (a.x + b.x) + (cc.x + d.x);
        acc.y += (a.y + b.y) + (cc.y + d.y);
        acc.z += (a.z + b.z) + (cc.z + d.z);
        acc.w += (a.w + b.w) + (cc.w + d.w);
    }
    for (; e < s1; ++e) {
        int s = csr_src[e];
        float4 a = p4[(size_t)s * 16 + sub];
        acc.x += a.x; acc.y += a.y; acc.z += a.z; acc.w += a.w;
    }
    float inv = 1.f / fmaxf((float)(s1 - s0), 1.f);
    float4 self = ((const float4*)selfp)[(size_t)node * 16 + sub];
    float4 bs = ((const float4*)bias)[sub];
    float4 r;
    r.x = fmaxf(fmaf(acc.x, inv, bs.x + self.x), 0.f);
    r.y = fmaxf(fmaf(acc.y, inv, bs.y + self.y), 0.f);
    r.z = fmaxf(fmaf(acc.z, inv, bs.z + self.z), 0.f);
    r.w = fmaxf(fmaf(acc.w, inv, bs.w + self.w), 0.f);
    ((float4*)out)[(size_t)node * 16 + sub] = r;
}

// ---------------- query head: out = relu(A[u]+B[v]+t*wt+bm1) . Wm2 + bm2 ----------------
// grid-stride; 16 lanes per query (float4/lane), constants hoisted.
__global__ __launch_bounds__(256) void query_kernel(
    const int* __restrict__ uv, const float* __restrict__ tf,
    const float* __restrict__ A, const float* __restrict__ B,
    const float* __restrict__ wt, const float* __restrict__ bm1,
    const float* __restrict__ Wm2, const float* __restrict__ bm2,
    float* __restrict__ out) {
    int sub = threadIdx.x & 15;
    int gidx = (blockIdx.x * 256 + threadIdx.x) >> 4;
    int ngroups = (gridDim.x * 256) >> 4;
    const float4* A4 = (const float4*)A;
    const float4* B4 = (const float4*)B;
    const int2* uv2 = (const int2*)uv;
    float4 wt4 = ((const float4*)wt)[sub];
    float4 bm14 = ((const float4*)bm1)[sub];
    float4 wm24 = ((const float4*)Wm2)[sub];
    float bm2s = bm2[0];
#pragma unroll 2
    for (int q = gidx; q < NQ; q += ngroups) {
        int2 uvq = uv2[q];
        float t = tf[q];
        float4 a = A4[(size_t)uvq.x * 16 + sub];
        float4 b = B4[(size_t)uvq.y * 16 + sub];
        float zx = fmaxf(a.x + b.x + t * wt4.x + bm14.x, 0.f) * wm24.x;
        float zy = fmaxf(a.y + b.y + t * wt4.y + bm14.y, 0.f) * wm24.y;
        float zz = fmaxf(a.z + b.z + t * wt4.z + bm14.z, 0.f) * wm24.z;
        float zw = fmaxf(a.w + b.w + t * wt4.w + bm14.w, 0.f) * wm24.w;
        float s = (zx + zy) + (zz + zw);
        s += __shfl_down(s, 8, 16);
        s += __shfl_down(s, 4, 16);
        s += __shfl_down(s, 2, 16);
        s += __shfl_down(s, 1, 16);
        if (sub == 0) out[q] = s + bm2s;
    }
}

extern "C" void kernel_launch(void* const* d_in, const int* in_sizes, int n_in,
                              void* d_out, int out_size, void* d_ws, size_t ws_size,
                              hipStream_t stream) {
    const float* x   = (const float*)d_in[0];
    const int*   ei  = (const int*)d_in[1];
    const int*   uv  = (const int*)d_in[2];
    const float* tf  = (const float*)d_in[3];
    const float* W1l = (const float*)d_in[4];
    const float* b1  = (const float*)d_in[5];
    const float* W1r = (const float*)d_in[6];
    const float* W2l = (const float*)d_in[7];
    const float* b2  = (const float*)d_in[8];
    const float* W2r = (const float*)d_in[9];
    const float* Wm1 = (const float*)d_in[10];
    const float* bm1 = (const float*)d_in[11];
    const float* Wm2 = (const float*)d_in[12];
    const float* bm2 = (const float*)d_in[13];
    float* out = (float*)d_out;

    char* ws = (char*)d_ws;
    size_t off = 0;
    auto take = [&](size_t bytes) -> void* {
        void* p = ws + off;
        off = (off + bytes + 255) & ~(size_t)255;
        return p;
    };
    int* row_start = (int*)take((NN + 1) * sizeof(int));
    int* cnt       = (int*)take((size_t)NN * sizeof(int));
    int* csr_src   = (int*)take((size_t)NE * sizeof(int));
    unsigned* tmp  = (unsigned*)take((size_t)NE * sizeof(unsigned));
    int* bsum      = (int*)take(64 * sizeof(int));
    int* bucket_cursor = (int*)take((NBUCKET + 1) * sizeof(int));
    float* WmA = (float*)take(64 * 64 * sizeof(float));
    float* WmB = (float*)take(64 * 64 * sizeof(float));
    float* wt  = (float*)take(64 * sizeof(float));
    float* buf0 = (float*)take((size_t)NN * 64 * sizeof(float));
    float* buf1 = (float*)take((size_t)NN * 64 * sizeof(float));
    float* buf2 = (float*)take((size_t)NN * 64 * sizeof(float));
    (void)in_sizes; (void)n_in; (void)out_size; (void)ws_size;

    const int* esrc = ei;
    const int* edst = ei + NE;

    // CSR build: count -> scan (row_start + bucket cursors) -> binned 2-pass fill
    hipMemsetAsync(cnt, 0, NN * sizeof(int), stream);
    count_kernel<<<(NE + 255) / 256, 256, 0, stream>>>(edst, cnt);
    scan_sum_kernel<<<SBLK, 256, 0, stream>>>(cnt, bsum);
    scan_block_kernel<<<1, 64, 0, stream>>>(bsum);
    scan_write_kernel<<<SBLK, 256, 0, stream>>>(bsum, row_start, cnt, bucket_cursor);
    bin_scatter_kernel<<<(NE + 255) / 256, 256, 0, stream>>>(esrc, edst, bucket_cursor, tmp);
    csr_fill_kernel<<<NBUCKET, 256, 0, stream>>>(row_start, tmp, csr_src);
    prep_wm1_kernel<<<16, 256, 0, stream>>>(Wm1, WmA, WmB, wt);

    // Layer 1: p1 = x@W1l.T (buf0), xr = x@W1r.T (buf1); h1 = relu(mean+b1+xr) (buf2)
    dual_gemm_kernel<128><<<(NN + 63) / 64, 256, 0, stream>>>(x, W1l, W1r, buf0, buf1);
    agg_kernel<<<(NN + 15) / 16, 256, 0, stream>>>(buf0, buf1, b1, row_start, csr_src, buf2);
    // Layer 2
    dual_gemm_kernel<64><<<(NN + 63) / 64, 256, 0, stream>>>(buf2, W2l, W2r, buf0, buf1);
    agg_kernel<<<(NN + 15) / 16, 256, 0, stream>>>(buf0, buf1, b2, row_start, csr_src, buf2);
    // MLP factorization: A = h2@WmA.T (buf0), B = h2@WmB.T (buf1)
    dual_gemm_kernel<64><<<(NN + 63) / 64, 256, 0, stream>>>(buf2, WmA, WmB, buf0, buf1);
    // Per-query head
    query_kernel<<<2048, 256, 0, stream>>>(uv, tf, buf0, buf1, wt, bm1, Wm2, bm2, out);
}

// Round 6
// 260.175 us; speedup vs baseline: 2.0300x; 2.0300x over previous
//
#include <hip/hip_runtime.h>
#include <hip/hip_fp16.h>

// EtaGNN: 2x SAGE-conv (mean agg) + factorized MLP link predictor.
// Strategy: project-then-aggregate (linearity of mean), CSR gather (no f32 atomics),
// factorized query head (A[u]+B[v]+t*wt).
// R1: register-light dual_gemm (R0 spilled at 256 VGPR).
// R2: X tile in LDS, agg/query 16-lane float4 groups.
// R3: GEMM v4 - W via prefetched global float4, 64 rows/block; Wm1 pre-split.
// R4: binned fill REGRESSED 5x (800k atomics over 391 counters / ~25 cache lines
//     -> cross-XCD contention, 280us at 0.1% VALU). Reverted to direct fill.
// R5: halve gather traffic: neighbor-projection and query A/B buffers stored fp16
//     (gathered rows 256B->128B); all accumulation stays f32. Self path f32.

constexpr int NN = 50000;   // nodes
constexpr int NE = 800000;  // edges
constexpr int NQ = 400000;  // queries

// ---------------- CSR build ----------------
__global__ void count_kernel(const int* __restrict__ dst, int* __restrict__ cnt) {
    int e = blockIdx.x * 256 + threadIdx.x;
    if (e < NE) atomicAdd(&cnt[dst[e]], 1);
}

constexpr int SCHUNK = 1024;
constexpr int SBLK = (NN + SCHUNK - 1) / SCHUNK;  // 49 blocks

__global__ void scan_sum_kernel(const int* __restrict__ cnt, int* __restrict__ bsum) {
    __shared__ int sd[256];
    int t = threadIdx.x;
    int base = blockIdx.x * SCHUNK;
    int s = 0;
#pragma unroll
    for (int j = 0; j < 4; ++j) {
        int i = base + t + j * 256;
        if (i < NN) s += cnt[i];
    }
    sd[t] = s; __syncthreads();
    for (int off = 128; off > 0; off >>= 1) {
        if (t < off) sd[t] += sd[t + off];
        __syncthreads();
    }
    if (t == 0) bsum[blockIdx.x] = sd[0];
}

__global__ void scan_block_kernel(int* bsum) {  // 1 wave, exclusive scan in place
    int t = threadIdx.x;
    int orig = (t < SBLK) ? bsum[t] : 0;
    int v = orig;
#pragma unroll
    for (int off = 1; off < 64; off <<= 1) {
        int w = __shfl_up(v, off);
        if (t >= off) v += w;
    }
    if (t < SBLK) bsum[t] = v - orig;
}

__global__ void scan_write_kernel(const int* __restrict__ bsum, int* __restrict__ row_start,
                                  int* __restrict__ cursor /* in: counts, out: cursor */) {
    __shared__ int wsum[4];
    int t = threadIdx.x, lane = t & 63, wid = t >> 6;
    int base = blockIdx.x * SCHUNK;
    int v[4]; int s = 0;
#pragma unroll
    for (int j = 0; j < 4; ++j) {
        int i = base + t * 4 + j;
        v[j] = (i < NN) ? cursor[i] : 0;
        s += v[j];
    }
    int orig = s;
#pragma unroll
    for (int off = 1; off < 64; off <<= 1) {
        int w = __shfl_up(s, off);
        if (lane >= off) s += w;
    }
    if (lane == 63) wsum[wid] = s;
    __syncthreads();
    int woff = 0;
    for (int w = 0; w < wid; ++w) woff += wsum[w];
    int excl = bsum[blockIdx.x] + woff + (s - orig);
#pragma unroll
    for (int j = 0; j < 4; ++j) {
        int i = base + t * 4 + j;
        if (i <= NN) {
            row_start[i] = excl;
            if (i < NN) { cursor[i] = excl; excl += v[j]; }
        }
    }
}

__global__ void fill_kernel(const int* __restrict__ src, const int* __restrict__ dst,
                            int* __restrict__ cursor, int* __restrict__ csr_src) {
    int e = blockIdx.x * 256 + threadIdx.x;
    if (e < NE) {
        int p = atomicAdd(&cursor[dst[e]], 1);
        csr_src[p] = src[e];
    }
}

// ---------------- Wm1 split: WmA[64][64], WmB[64][64], wt[64] ----------------
__global__ void prep_wm1_kernel(const float* __restrict__ Wm1, float* __restrict__ WmA,
                                float* __restrict__ WmB, float* __restrict__ wt) {
    int t = blockIdx.x * 256 + threadIdx.x;
    if (t < 64 * 64) {
        int c = t >> 6, k = t & 63;
        WmA[t] = Wm1[c * 129 + k];
        WmB[t] = Wm1[c * 129 + 64 + k];
    }
    if (t < 64) wt[t] = Wm1[t * 129 + 128];
}

// ---------------- dual GEMM: outA = in @ Wa.T, outB = in @ Wb.T  (Cout=64, row stride K) ----
// 256 threads = 4 waves; wave owns 16 rows, lane owns 1 col of each output.
// X tile in LDS (uniform broadcast b128 reads); W streamed from global per-thread
// (own row, L1/L2-resident) with 1-step register prefetch. One barrier total.
template <typename T>
__device__ inline void store_conv(T* p, float v);
template <> __device__ inline void store_conv<float>(float* p, float v) { *p = v; }
template <> __device__ inline void store_conv<__half>(__half* p, float v) { *p = __float2half(v); }

template <int K, typename TA, typename TB>
__global__ __launch_bounds__(256, 4) void dual_gemm_kernel(
    const float* __restrict__ in,
    const float* __restrict__ Wa, const float* __restrict__ Wb,
    TA* __restrict__ outA, TB* __restrict__ outB) {
    __shared__ float X[64][K];
    int t = threadIdx.x;
    int c = t & 63, g = t >> 6;
    int rbase = blockIdx.x * 64;
    constexpr int KV = K / 4;
    {
        const float4* in4 = (const float4*)in;
        float4* X4 = (float4*)&X[0][0];
        for (int idx = t; idx < 64 * KV; idx += 256) {
            int r = idx / KV, kv = idx - r * KV;
            int gr = rbase + r; if (gr >= NN) gr = NN - 1;  // clamp; stores guarded
            X4[idx] = in4[(size_t)gr * KV + kv];
        }
    }
    float accA[16], accB[16];
#pragma unroll
    for (int j = 0; j < 16; ++j) { accA[j] = 0.f; accB[j] = 0.f; }
    const float* wap = Wa + (size_t)c * K;
    const float* wbp = Wb + (size_t)c * K;
    float4 wa = *(const float4*)wap;
    float4 wb = *(const float4*)wbp;
    __syncthreads();
#pragma unroll 2
    for (int k2 = 0; k2 < K; k2 += 4) {
        float4 wan = wa, wbn = wb;
        if (k2 + 4 < K) {
            wan = *(const float4*)(wap + k2 + 4);
            wbn = *(const float4*)(wbp + k2 + 4);
        }
#pragma unroll
        for (int j = 0; j < 16; ++j) {
            float4 xv = *reinterpret_cast<const float4*>(&X[g * 16 + j][k2]);
            accA[j] = fmaf(xv.x, wa.x, accA[j]);
            accB[j] = fmaf(xv.x, wb.x, accB[j]);
            accA[j] = fmaf(xv.y, wa.y, accA[j]);
            accB[j] = fmaf(xv.y, wb.y, accB[j]);
            accA[j] = fmaf(xv.z, wa.z, accA[j]);
            accB[j] = fmaf(xv.z, wb.z, accB[j]);
            accA[j] = fmaf(xv.w, wa.w, accA[j]);
            accB[j] = fmaf(xv.w, wb.w, accB[j]);
        }
        wa = wan; wb = wbn;
    }
#pragma unroll
    for (int j = 0; j < 16; ++j) {
        int gr = rbase + g * 16 + j;
        if (gr < NN) {
            store_conv<TA>(&outA[(size_t)gr * 64 + c], accA[j]);
            store_conv<TB>(&outB[(size_t)gr * 64 + c], accB[j]);
        }
    }
}

__device__ inline float2 u2f2(unsigned u) {
    __half2 h = *reinterpret_cast<__half2*>(&u);
    return __half22float2(h);
}

// ---------------- aggregation: out = relu(sum(p[src])/max(deg,1) + bias + selfp) ----------------
// p is fp16 rows (128B); 16 lanes per node (uint2 = 4 halves/lane), f32 accumulate.
__global__ __launch_bounds__(256) void agg_kernel(
    const __half* __restrict__ p, const float* __restrict__ selfp,
    const float* __restrict__ bias, const int* __restrict__ row_start,
    const int* __restrict__ csr_src, float* __restrict__ out) {
    int node = blockIdx.x * 16 + (threadIdx.x >> 4);
    int sub = threadIdx.x & 15;
    if (node >= NN) return;
    const uint2* p2 = (const uint2*)p;
    int s0 = row_start[node], s1 = row_start[node + 1];
    float4 acc = make_float4(0.f, 0.f, 0.f, 0.f);
    int e = s0;
    for (; e + 4 <= s1; e += 4) {
        int i0 = csr_src[e + 0], i1 = csr_src[e + 1];
        int i2 = csr_src[e + 2], i3 = csr_src[e + 3];
        uint2 a = p2[(size_t)i0 * 16 + sub];
        uint2 b = p2[(size_t)i1 * 16 + sub];
        uint2 cc = p2[(size_t)i2 * 16 + sub];
        uint2 d = p2[(size_t)i3 * 16 + sub];
        float2 a0 = u2f2(a.x), a1 = u2f2(a.y);
        float2 b0 = u2f2(b.x), b1 = u2f2(b.y);
        float2 c0 = u2f2(cc.x), c1 = u2f2(cc.y);
        float2 d0 = u2f2(d.x), d1 = u2f2(d.y);
        acc.x += (a0.x + b0.x) + (c0.x + d0.x);
        acc.y += (a0.y + b0.y) + (c0.y + d0.y);
        acc.z += (a1.x + b1.x) + (c1.x + d1.x);
        acc.w += (a1.y + b1.y) + (c1.y + d1.y);
    }
    for (; e < s1; ++e) {
        int s = csr_src[e];
        uint2 a = p2[(size_t)s * 16 + sub];
        float2 a0 = u2f2(a.x), a1 = u2f2(a.y);
        acc.x += a0.x; acc.y += a0.y; acc.z += a1.x; acc.w += a1.y;
    }
    float inv = 1.f / fmaxf((float)(s1 - s0), 1.f);
    float4 self = ((const float4*)selfp)[(size_t)node * 16 + sub];
    float4 bs = ((const float4*)bias)[sub];
    float4 r;
    r.x = fmaxf(fmaf(acc.x, inv, bs.x + self.x), 0.f);
    r.y = fmaxf(fmaf(acc.y, inv, bs.y + self.y), 0.f);
    r.z = fmaxf(fmaf(acc.z, inv, bs.z + self.z), 0.f);
    r.w = fmaxf(fmaf(acc.w, inv, bs.w + self.w), 0.f);
    ((float4*)out)[(size_t)node * 16 + sub] = r;
}

// ---------------- query head: out = relu(A[u]+B[v]+t*wt+bm1) . Wm2 + bm2 ----------------
// A,B fp16 rows (128B); grid-stride; 16 lanes per query (4 halves/lane), f32 math.
__global__ __launch_bounds__(256) void query_kernel(
    const int* __restrict__ uv, const float* __restrict__ tf,
    const __half* __restrict__ A, const __half* __restrict__ B,
    const float* __restrict__ wt, const float* __restrict__ bm1,
    const float* __restrict__ Wm2, const float* __restrict__ bm2,
    float* __restrict__ out) {
    int sub = threadIdx.x & 15;
    int gidx = (blockIdx.x * 256 + threadIdx.x) >> 4;
    int ngroups = (gridDim.x * 256) >> 4;
    const uint2* A2 = (const uint2*)A;
    const uint2* B2 = (const uint2*)B;
    const int2* uv2 = (const int2*)uv;
    float4 wt4 = ((const float4*)wt)[sub];
    float4 bm14 = ((const float4*)bm1)[sub];
    float4 wm24 = ((const float4*)Wm2)[sub];
    float bm2s = bm2[0];
#pragma unroll 2
    for (int q = gidx; q < NQ; q += ngroups) {
        int2 uvq = uv2[q];
        float t = tf[q];
        uint2 au = A2[(size_t)uvq.x * 16 + sub];
        uint2 bv = B2[(size_t)uvq.y * 16 + sub];
        float2 a0 = u2f2(au.x), a1 = u2f2(au.y);
        float2 b0 = u2f2(bv.x), b1 = u2f2(bv.y);
        float zx = fmaxf(a0.x + b0.x + t * wt4.x + bm14.x, 0.f) * wm24.x;
        float zy = fmaxf(a0.y + b0.y + t * wt4.y + bm14.y, 0.f) * wm24.y;
        float zz = fmaxf(a1.x + b1.x + t * wt4.z + bm14.z, 0.f) * wm24.z;
        float zw = fmaxf(a1.y + b1.y + t * wt4.w + bm14.w, 0.f) * wm24.w;
        float s = (zx + zy) + (zz + zw);
        s += __shfl_down(s, 8, 16);
        s += __shfl_down(s, 4, 16);
        s += __shfl_down(s, 2, 16);
        s += __shfl_down(s, 1, 16);
        if (sub == 0) out[q] = s + bm2s;
    }
}

extern "C" void kernel_launch(void* const* d_in, const int* in_sizes, int n_in,
                              void* d_out, int out_size, void* d_ws, size_t ws_size,
                              hipStream_t stream) {
    const float* x   = (const float*)d_in[0];
    const int*   ei  = (const int*)d_in[1];
    const int*   uv  = (const int*)d_in[2];
    const float* tf  = (const float*)d_in[3];
    const float* W1l = (const float*)d_in[4];
    const float* b1  = (const float*)d_in[5];
    const float* W1r = (const float*)d_in[6];
    const float* W2l = (const float*)d_in[7];
    const float* b2  = (const float*)d_in[8];
    const float* W2r = (const float*)d_in[9];
    const float* Wm1 = (const float*)d_in[10];
    const float* bm1 = (const float*)d_in[11];
    const float* Wm2 = (const float*)d_in[12];
    const float* bm2 = (const float*)d_in[13];
    float* out = (float*)d_out;

    char* ws = (char*)d_ws;
    size_t off = 0;
    auto take = [&](size_t bytes) -> void* {
        void* p = ws + off;
        off = (off + bytes + 255) & ~(size_t)255;
        return p;
    };
    int* row_start = (int*)take((NN + 1) * sizeof(int));
    int* cursor    = (int*)take((size_t)NN * sizeof(int));
    int* csr_src   = (int*)take((size_t)NE * sizeof(int));
    int* bsum      = (int*)take(64 * sizeof(int));
    float* WmA = (float*)take(64 * 64 * sizeof(float));
    float* WmB = (float*)take(64 * 64 * sizeof(float));
    float* wt  = (float*)take(64 * sizeof(float));
    __half* ph   = (__half*)take((size_t)NN * 64 * sizeof(__half));  // neighbor proj / A
    __half* ph2  = (__half*)take((size_t)NN * 64 * sizeof(__half));  // B
    float* buf1 = (float*)take((size_t)NN * 64 * sizeof(float));     // self proj
    float* buf2 = (float*)take((size_t)NN * 64 * sizeof(float));     // layer output
    (void)in_sizes; (void)n_in; (void)out_size; (void)ws_size;

    const int* esrc = ei;
    const int* edst = ei + NE;

    // CSR build (counts -> exclusive scan -> fill) + Wm1 split
    hipMemsetAsync(cursor, 0, NN * sizeof(int), stream);
    count_kernel<<<(NE + 255) / 256, 256, 0, stream>>>(edst, cursor);
    scan_sum_kernel<<<SBLK, 256, 0, stream>>>(cursor, bsum);
    scan_block_kernel<<<1, 64, 0, stream>>>(bsum);
    scan_write_kernel<<<SBLK, 256, 0, stream>>>(bsum, row_start, cursor);
    fill_kernel<<<(NE + 255) / 256, 256, 0, stream>>>(esrc, edst, cursor, csr_src);
    prep_wm1_kernel<<<16, 256, 0, stream>>>(Wm1, WmA, WmB, wt);

    // Layer 1: p1 = x@W1l.T (fp16 ph), xr = x@W1r.T (f32 buf1); h1 = relu(mean+b1+xr) (buf2)
    dual_gemm_kernel<128, __half, float><<<(NN + 63) / 64, 256, 0, stream>>>(x, W1l, W1r, ph, buf1);
    agg_kernel<<<(NN + 15) / 16, 256, 0, stream>>>(ph, buf1, b1, row_start, csr_src, buf2);
    // Layer 2
    dual_gemm_kernel<64, __half, float><<<(NN + 63) / 64, 256, 0, stream>>>(buf2, W2l, W2r, ph, buf1);
    agg_kernel<<<(NN + 15) / 16, 256, 0, stream>>>(ph, buf1, b2, row_start, csr_src, buf2);
    // MLP factorization: A = h2@WmA.T (fp16 ph), B = h2@WmB.T (fp16 ph2)
    dual_gemm_kernel<64, __half, __half><<<(NN + 63) / 64, 256, 0, stream>>>(buf2, WmA, WmB, ph, ph2);
    // Per-query head
    query_kernel<<<2048, 256, 0, stream>>>(uv, tf, ph, ph2, wt, bm1, Wm2, bm2, out);
}

// Round 7
// 252.652 us; speedup vs baseline: 2.0904x; 1.0298x over previous
//
#include <hip/hip_runtime.h>
#include <hip/hip_fp16.h>

// EtaGNN: 2x SAGE-conv (mean agg) + factorized MLP link predictor.
// Strategy: project-then-aggregate (linearity of mean), CSR gather (no f32 atomics),
// factorized query head (A[u]+B[v]+t*wt).
// R1: register-light dual_gemm (R0 spilled at 256 VGPR).
// R2: X tile in LDS, agg/query 16-lane float4 groups.
// R3: GEMM v4 - W via prefetched global float4, 64 rows/block; Wm1 pre-split.
// R4: binned fill REGRESSED 5x (atomics over 391 global counters -> cross-XCD
//     contention, 137ns/atomic). Lesson: few-counter global atomics are poison.
// R5: fp16 storage for gathered buffers (rows 256B->128B), f32 accumulate.
// R6: GEMM v5 - 2 cols/lane (8 LDS reads per k2-step instead of 16; LDS pipe was
//     co-bottleneck). CSR build atomic-free: per-block LDS histograms -> exact
//     offsets via scan -> LDS-cursor scatter -> per-bucket count+fill.

constexpr int NN = 50000;   // nodes
constexpr int NE = 800000;  // edges
constexpr int NQ = 400000;  // queries
constexpr int NBUCKET = (NN + 127) >> 7;       // 391 buckets of 128 nodes
constexpr int EPB = 4096;                      // edges per scatter block
constexpr int NBLK_S = (NE + EPB - 1) / EPB;   // 196 scatter blocks

// ---------------- CSR build (atomic-free binned sort) ----------------
// (a) per-block bucket histogram
__global__ __launch_bounds__(256) void hist_kernel(const int* __restrict__ dst,
                                                   int* __restrict__ hist) {
    __shared__ int h[NBUCKET];
    int t = threadIdx.x, blk = blockIdx.x;
    for (int k = t; k < NBUCKET; k += 256) h[k] = 0;
    __syncthreads();
    int base = blk * EPB;
#pragma unroll
    for (int i = 0; i < EPB / 256; ++i) {
        int e = base + t + i * 256;
        if (e < NE) atomicAdd(&h[dst[e] >> 7], 1);
    }
    __syncthreads();
    for (int k = t; k < NBUCKET; k += 256) hist[blk * NBUCKET + k] = h[k];
}

// (b) hist[block][bucket] -> exact scatter offsets; bucket_base[k] = window starts
__global__ __launch_bounds__(512) void scan_hist_kernel(int* __restrict__ hist,
                                                        int* __restrict__ bucket_base) {
    __shared__ int sd[512];
    int k = threadIdx.x;
    int tot = 0;
    if (k < NBUCKET)
        for (int b = 0; b < NBLK_S; ++b) tot += hist[b * NBUCKET + k];
    sd[k] = tot; __syncthreads();
    for (int off = 1; off < 512; off <<= 1) {
        int v = sd[k];
        if (k >= off) v += sd[k - off];
        __syncthreads(); sd[k] = v; __syncthreads();
    }
    int base = sd[k] - tot;  // exclusive
    if (k <= NBUCKET) bucket_base[k] = base;
    if (k < NBUCKET) {
        int run = base;
        for (int b = 0; b < NBLK_S; ++b) {
            int h = hist[b * NBUCKET + k];
            hist[b * NBUCKET + k] = run;
            run += h;
        }
    }
}

// (c) scatter edges into bucket-ordered tmp via per-block LDS cursors (no global atomics)
__global__ __launch_bounds__(256) void scatter_kernel(const int* __restrict__ src,
                                                      const int* __restrict__ dst,
                                                      const int* __restrict__ hist,
                                                      unsigned* __restrict__ tmp) {
    __shared__ int cur[NBUCKET];
    int t = threadIdx.x, blk = blockIdx.x;
    for (int k = t; k < NBUCKET; k += 256) cur[k] = hist[blk * NBUCKET + k];
    __syncthreads();
    int base = blk * EPB;
#pragma unroll
    for (int i = 0; i < EPB / 256; ++i) {
        int e = base + t + i * 256;
        if (e < NE) {
            int d = dst[e];
            int p = atomicAdd(&cur[d >> 7], 1);
            tmp[p] = ((unsigned)(d & 127) << 16) | (unsigned)src[e];
        }
    }
}

// (d) per-bucket node counts from tmp (LDS atomics only)
__global__ __launch_bounds__(256) void bucket_count_kernel(const int* __restrict__ bucket_base,
                                                           const unsigned* __restrict__ tmp,
                                                           int* __restrict__ cnt) {
    __shared__ int c[128];
    int t = threadIdx.x, b = blockIdx.x;
    if (t < 128) c[t] = 0;
    __syncthreads();
    int s = bucket_base[b], e1 = bucket_base[b + 1];
    for (int i = s + t; i < e1; i += 256) atomicAdd(&c[tmp[i] >> 16], 1);
    __syncthreads();
    int node = (b << 7) + t;
    if (t < 128 && node < NN) cnt[node] = c[t];
}

constexpr int SCHUNK = 1024;
constexpr int SBLK = (NN + SCHUNK - 1) / SCHUNK;  // 49 blocks

__global__ void scan_sum_kernel(const int* __restrict__ cnt, int* __restrict__ bsum) {
    __shared__ int sd[256];
    int t = threadIdx.x;
    int base = blockIdx.x * SCHUNK;
    int s = 0;
#pragma unroll
    for (int j = 0; j < 4; ++j) {
        int i = base + t + j * 256;
        if (i < NN) s += cnt[i];
    }
    sd[t] = s; __syncthreads();
    for (int off = 128; off > 0; off >>= 1) {
        if (t < off) sd[t] += sd[t + off];
        __syncthreads();
    }
    if (t == 0) bsum[blockIdx.x] = sd[0];
}

__global__ void scan_block_kernel(int* bsum) {  // 1 wave, exclusive scan in place
    int t = threadIdx.x;
    int orig = (t < SBLK) ? bsum[t] : 0;
    int v = orig;
#pragma unroll
    for (int off = 1; off < 64; off <<= 1) {
        int w = __shfl_up(v, off);
        if (t >= off) v += w;
    }
    if (t < SBLK) bsum[t] = v - orig;
}

__global__ void scan_write_kernel(const int* __restrict__ bsum, int* __restrict__ row_start,
                                  const int* __restrict__ cnt) {
    __shared__ int wsum[4];
    int t = threadIdx.x, lane = t & 63, wid = t >> 6;
    int base = blockIdx.x * SCHUNK;
    int v[4]; int s = 0;
#pragma unroll
    for (int j = 0; j < 4; ++j) {
        int i = base + t * 4 + j;
        v[j] = (i < NN) ? cnt[i] : 0;
        s += v[j];
    }
    int orig = s;
#pragma unroll
    for (int off = 1; off < 64; off <<= 1) {
        int w = __shfl_up(s, off);
        if (lane >= off) s += w;
    }
    if (lane == 63) wsum[wid] = s;
    __syncthreads();
    int woff = 0;
    for (int w = 0; w < wid; ++w) woff += wsum[w];
    int excl = bsum[blockIdx.x] + woff + (s - orig);
#pragma unroll
    for (int j = 0; j < 4; ++j) {
        int i = base + t * 4 + j;
        if (i <= NN) {
            row_start[i] = excl;
            excl += (i < NN) ? v[j] : 0;
        }
    }
}

// (f) per-bucket: LDS cursors from row_start, fill csr_src within contiguous window
__global__ __launch_bounds__(256) void csr_fill_kernel(const int* __restrict__ row_start,
                                                       const unsigned* __restrict__ tmp,
                                                       int* __restrict__ csr_src) {
    __shared__ int cur[128];
    int b = blockIdx.x;
    int node_base = b << 7;
    int n_nodes = NN - node_base; if (n_nodes > 128) n_nodes = 128;
    int t = threadIdx.x;
    if (t < n_nodes) cur[t] = row_start[node_base + t];
    __syncthreads();
    int bstart = row_start[node_base];
    int bend = row_start[node_base + n_nodes];
    for (int e = bstart + t; e < bend; e += 256) {
        unsigned pk = tmp[e];
        int p = atomicAdd(&cur[pk >> 16], 1);
        csr_src[p] = (int)(pk & 0xFFFFu);
    }
}

// ---------------- Wm1 split: WmA[64][64], WmB[64][64], wt[64] ----------------
__global__ void prep_wm1_kernel(const float* __restrict__ Wm1, float* __restrict__ WmA,
                                float* __restrict__ WmB, float* __restrict__ wt) {
    int t = blockIdx.x * 256 + threadIdx.x;
    if (t < 64 * 64) {
        int c = t >> 6, k = t & 63;
        WmA[t] = Wm1[c * 129 + k];
        WmB[t] = Wm1[c * 129 + 64 + k];
    }
    if (t < 64) wt[t] = Wm1[t * 129 + 128];
}

// ---------------- dual GEMM v5: outA = in @ Wa.T, outB = in @ Wb.T (Cout=64) -------------
// 256 threads = 4 waves; wave owns 16 rows. lane = 32*rh + cl: handles cols {cl, cl+32},
// rows rh*8..rh*8+7 -> per k2-step only 8 ds_read_b128 (2-addr broadcast, free) per wave
// against 128 FMAs. W streamed from global per-lane with 1-step register prefetch.
template <typename T>
__device__ inline void store_conv(T* p, float v);
template <> __device__ inline void store_conv<float>(float* p, float v) { *p = v; }
template <> __device__ inline void store_conv<__half>(__half* p, float v) { *p = __float2half(v); }

template <int K, typename TA, typename TB>
__global__ __launch_bounds__(256, 4) void dual_gemm_kernel(
    const float* __restrict__ in,
    const float* __restrict__ Wa, const float* __restrict__ Wb,
    TA* __restrict__ outA, TB* __restrict__ outB) {
    __shared__ float X[64][K];
    int t = threadIdx.x;
    int lane = t & 63, g = t >> 6;
    int cl = lane & 31, rh = lane >> 5;
    int rbase = blockIdx.x * 64;
    constexpr int KV = K / 4;
    {
        const float4* in4 = (const float4*)in;
        float4* X4 = (float4*)&X[0][0];
        for (int idx = t; idx < 64 * KV; idx += 256) {
            int r = idx / KV, kv = idx - r * KV;
            int gr = rbase + r; if (gr >= NN) gr = NN - 1;  // clamp; stores guarded
            X4[idx] = in4[(size_t)gr * KV + kv];
        }
    }
    float accA0[8], accA1[8], accB0[8], accB1[8];
#pragma unroll
    for (int j = 0; j < 8; ++j) { accA0[j] = 0.f; accA1[j] = 0.f; accB0[j] = 0.f; accB1[j] = 0.f; }
    const float* wa0p = Wa + (size_t)cl * K;
    const float* wa1p = Wa + (size_t)(cl + 32) * K;
    const float* wb0p = Wb + (size_t)cl * K;
    const float* wb1p = Wb + (size_t)(cl + 32) * K;
    float4 wa0 = *(const float4*)wa0p;
    float4 wa1 = *(const float4*)wa1p;
    float4 wb0 = *(const float4*)wb0p;
    float4 wb1 = *(const float4*)wb1p;
    int rowb = g * 16 + rh * 8;
    __syncthreads();
    for (int k2 = 0; k2 < K; k2 += 4) {
        float4 na0 = wa0, na1 = wa1, nb0 = wb0, nb1 = wb1;
        if (k2 + 4 < K) {
            na0 = *(const float4*)(wa0p + k2 + 4);
            na1 = *(const float4*)(wa1p + k2 + 4);
            nb0 = *(const float4*)(wb0p + k2 + 4);
            nb1 = *(const float4*)(wb1p + k2 + 4);
        }
#pragma unroll
        for (int j = 0; j < 8; ++j) {
            float4 xv = *reinterpret_cast<const float4*>(&X[rowb + j][k2]);
            accA0[j] = fmaf(xv.x, wa0.x, accA0[j]);
            accA1[j] = fmaf(xv.x, wa1.x, accA1[j]);
            accB0[j] = fmaf(xv.x, wb0.x, accB0[j]);
            accB1[j] = fmaf(xv.x, wb1.x, accB1[j]);
            accA0[j] = fmaf(xv.y, wa0.y, accA0[j]);
            accA1[j] = fmaf(xv.y, wa1.y, accA1[j]);
            accB0[j] = fmaf(xv.y, wb0.y, accB0[j]);
            accB1[j] = fmaf(xv.y, wb1.y, accB1[j]);
            accA0[j] = fmaf(xv.z, wa0.z, accA0[j]);
            accA1[j] = fmaf(xv.z, wa1.z, accA1[j]);
            accB0[j] = fmaf(xv.z, wb0.z, accB0[j]);
            accB1[j] = fmaf(xv.z, wb1.z, accB1[j]);
            accA0[j] = fmaf(xv.w, wa0.w, accA0[j]);
            accA1[j] = fmaf(xv.w, wa1.w, accA1[j]);
            accB0[j] = fmaf(xv.w, wb0.w, accB0[j]);
            accB1[j] = fmaf(xv.w, wb1.w, accB1[j]);
        }
        wa0 = na0; wa1 = na1; wb0 = nb0; wb1 = nb1;
    }
#pragma unroll
    for (int j = 0; j < 8; ++j) {
        int gr = rbase + rowb + j;
        if (gr < NN) {
            store_conv<TA>(&outA[(size_t)gr * 64 + cl], accA0[j]);
            store_conv<TA>(&outA[(size_t)gr * 64 + cl + 32], accA1[j]);
            store_conv<TB>(&outB[(size_t)gr * 64 + cl], accB0[j]);
            store_conv<TB>(&outB[(size_t)gr * 64 + cl + 32], accB1[j]);
        }
    }
}

__device__ inline float2 u2f2(unsigned u) {
    __half2 h = *reinterpret_cast<__half2*>(&u);
    return __half22float2(h);
}

// ---------------- aggregation: out = relu(sum(p[src])/max(deg,1) + bias + selfp) ----------------
// p is fp16 rows (128B); 16 lanes per node (uint2 = 4 halves/lane), f32 accumulate.
__global__ __launch_bounds__(256) void agg_kernel(
    const __half* __restrict__ p, const float* __restrict__ selfp,
    const float* __restrict__ bias, const int* __restrict__ row_start,
    const int* __restrict__ csr_src, float* __restrict__ out) {
    int node = blockIdx.x * 16 + (threadIdx.x >> 4);
    int sub = threadIdx.x & 15;
    if (node >= NN) return;
    const uint2* p2 = (const uint2*)p;
    int s0 = row_start[node], s1 = row_start[node + 1];
    float4 acc = make_float4(0.f, 0.f, 0.f, 0.f);
    int e = s0;
    for (; e + 4 <= s1; e += 4) {
        int i0 = csr_src[e + 0], i1 = csr_src[e + 1];
        int i2 = csr_src[e + 2], i3 = csr_src[e + 3];
        uint2 a = p2[(size_t)i0 * 16 + sub];
        uint2 b = p2[(size_t)i1 * 16 + sub];
        uint2 cc = p2[(size_t)i2 * 16 + sub];
        uint2 d = p2[(size_t)i3 * 16 + sub];
        float2 a0 = u2f2(a.x), a1 = u2f2(a.y);
        float2 b0 = u2f2(b.x), b1 = u2f2(b.y);
        float2 c0 = u2f2(cc.x), c1 = u2f2(cc.y);
        float2 d0 = u2f2(d.x), d1 = u2f2(d.y);
        acc.x += (a0.x + b0.x) + (c0.x + d0.x);
        acc.y += (a0.y + b0.y) + (c0.y + d0.y);
        acc.z += (a1.x + b1.x) + (c1.x + d1.x);
        acc.w += (a1.y + b1.y) + (c1.y + d1.y);
    }
    for (; e < s1; ++e) {
        int s = csr_src[e];
        uint2 a = p2[(size_t)s * 16 + sub];
        float2 a0 = u2f2(a.x), a1 = u2f2(a.y);
        acc.x += a0.x; acc.y += a0.y; acc.z += a1.x; acc.w += a1.y;
    }
    float inv = 1.f / fmaxf((float)(s1 - s0), 1.f);
    float4 self = ((const float4*)selfp)[(size_t)node * 16 + sub];
    float4 bs = ((const float4*)bias)[sub];
    float4 r;
    r.x = fmaxf(fmaf(acc.x, inv, bs.x + self.x), 0.f);
    r.y = fmaxf(fmaf(acc.y, inv, bs.y + self.y), 0.f);
    r.z = fmaxf(fmaf(acc.z, inv, bs.z + self.z), 0.f);
    r.w = fmaxf(fmaf(acc.w, inv, bs.w + self.w), 0.f);
    ((float4*)out)[(size_t)node * 16 + sub] = r;
}

// ---------------- query head: out = relu(A[u]+B[v]+t*wt+bm1) . Wm2 + bm2 ----------------
// A,B fp16 rows (128B); grid-stride; 16 lanes per query (4 halves/lane), f32 math.
__global__ __launch_bounds__(256) void query_kernel(
    const int* __restrict__ uv, const float* __restrict__ tf,
    const __half* __restrict__ A, const __half* __restrict__ B,
    const float* __restrict__ wt, const float* __restrict__ bm1,
    const float* __restrict__ Wm2, const float* __restrict__ bm2,
    float* __restrict__ out) {
    int sub = threadIdx.x & 15;
    int gidx = (blockIdx.x * 256 + threadIdx.x) >> 4;
    int ngroups = (gridDim.x * 256) >> 4;
    const uint2* A2 = (const uint2*)A;
    const uint2* B2 = (const uint2*)B;
    const int2* uv2 = (const int2*)uv;
    float4 wt4 = ((const float4*)wt)[sub];
    float4 bm14 = ((const float4*)bm1)[sub];
    float4 wm24 = ((const float4*)Wm2)[sub];
    float bm2s = bm2[0];
#pragma unroll 2
    for (int q = gidx; q < NQ; q += ngroups) {
        int2 uvq = uv2[q];
        float t = tf[q];
        uint2 au = A2[(size_t)uvq.x * 16 + sub];
        uint2 bv = B2[(size_t)uvq.y * 16 + sub];
        float2 a0 = u2f2(au.x), a1 = u2f2(au.y);
        float2 b0 = u2f2(bv.x), b1 = u2f2(bv.y);
        float zx = fmaxf(a0.x + b0.x + t * wt4.x + bm14.x, 0.f) * wm24.x;
        float zy = fmaxf(a0.y + b0.y + t * wt4.y + bm14.y, 0.f) * wm24.y;
        float zz = fmaxf(a1.x + b1.x + t * wt4.z + bm14.z, 0.f) * wm24.z;
        float zw = fmaxf(a1.y + b1.y + t * wt4.w + bm14.w, 0.f) * wm24.w;
        float s = (zx + zy) + (zz + zw);
        s += __shfl_down(s, 8, 16);
        s += __shfl_down(s, 4, 16);
        s += __shfl_down(s, 2, 16);
        s += __shfl_down(s, 1, 16);
        if (sub == 0) out[q] = s + bm2s;
    }
}

extern "C" void kernel_launch(void* const* d_in, const int* in_sizes, int n_in,
                              void* d_out, int out_size, void* d_ws, size_t ws_size,
                              hipStream_t stream) {
    const float* x   = (const float*)d_in[0];
    const int*   ei  = (const int*)d_in[1];
    const int*   uv  = (const int*)d_in[2];
    const float* tf  = (const float*)d_in[3];
    const float* W1l = (const float*)d_in[4];
    const float* b1  = (const float*)d_in[5];
    const float* W1r = (const float*)d_in[6];
    const float* W2l = (const float*)d_in[7];
    const float* b2  = (const float*)d_in[8];
    const float* W2r = (const float*)d_in[9];
    const float* Wm1 = (const float*)d_in[10];
    const float* bm1 = (const float*)d_in[11];
    const float* Wm2 = (const float*)d_in[12];
    const float* bm2 = (const float*)d_in[13];
    float* out = (float*)d_out;

    char* ws = (char*)d_ws;
    size_t off = 0;
    auto take = [&](size_t bytes) -> void* {
        void* p = ws + off;
        off = (off + bytes + 255) & ~(size_t)255;
        return p;
    };
    int* row_start = (int*)take((NN + 1) * sizeof(int));
    int* cnt       = (int*)take((size_t)NN * sizeof(int));
    int* csr_src   = (int*)take((size_t)NE * sizeof(int));
    unsigned* tmp  = (unsigned*)take((size_t)NE * sizeof(unsigned));
    int* hist      = (int*)take((size_t)NBLK_S * NBUCKET * sizeof(int));
    int* bucket_base = (int*)take((NBUCKET + 1) * sizeof(int));
    int* bsum      = (int*)take(64 * sizeof(int));
    float* WmA = (float*)take(64 * 64 * sizeof(float));
    float* WmB = (float*)take(64 * 64 * sizeof(float));
    float* wt  = (float*)take(64 * sizeof(float));
    __half* ph   = (__half*)take((size_t)NN * 64 * sizeof(__half));  // neighbor proj / A
    __half* ph2  = (__half*)take((size_t)NN * 64 * sizeof(__half));  // B
    float* buf1 = (float*)take((size_t)NN * 64 * sizeof(float));     // self proj
    float* buf2 = (float*)take((size_t)NN * 64 * sizeof(float));     // layer output
    (void)in_sizes; (void)n_in; (void)out_size; (void)ws_size;

    const int* esrc = ei;
    const int* edst = ei + NE;

    // CSR build: histogram -> offsets -> scatter -> per-bucket count -> scan -> fill
    hist_kernel<<<NBLK_S, 256, 0, stream>>>(edst, hist);
    scan_hist_kernel<<<1, 512, 0, stream>>>(hist, bucket_base);
    scatter_kernel<<<NBLK_S, 256, 0, stream>>>(esrc, edst, hist, tmp);
    bucket_count_kernel<<<NBUCKET, 256, 0, stream>>>(bucket_base, tmp, cnt);
    scan_sum_kernel<<<SBLK, 256, 0, stream>>>(cnt, bsum);
    scan_block_kernel<<<1, 64, 0, stream>>>(bsum);
    scan_write_kernel<<<SBLK, 256, 0, stream>>>(bsum, row_start, cnt);
    csr_fill_kernel<<<NBUCKET, 256, 0, stream>>>(row_start, tmp, csr_src);
    prep_wm1_kernel<<<16, 256, 0, stream>>>(Wm1, WmA, WmB, wt);

    // Layer 1: p1 = x@W1l.T (fp16 ph), xr = x@W1r.T (f32 buf1); h1 = relu(mean+b1+xr) (buf2)
    dual_gemm_kernel<128, __half, float><<<(NN + 63) / 64, 256, 0, stream>>>(x, W1l, W1r, ph, buf1);
    agg_kernel<<<(NN + 15) / 16, 256, 0, stream>>>(ph, buf1, b1, row_start, csr_src, buf2);
    // Layer 2
    dual_gemm_kernel<64, __half, float><<<(NN + 63) / 64, 256, 0, stream>>>(buf2, W2l, W2r, ph, buf1);
    agg_kernel<<<(NN + 15) / 16, 256, 0, stream>>>(ph, buf1, b2, row_start, csr_src, buf2);
    // MLP factorization: A = h2@WmA.T (fp16 ph), B = h2@WmB.T (fp16 ph2)
    dual_gemm_kernel<64, __half, __half><<<(NN + 63) / 64, 256, 0, stream>>>(buf2, WmA, WmB, ph, ph2);
    // Per-query head
    query_kernel<<<2048, 256, 0, stream>>>(uv, tf, ph, ph2, wt, bm1, Wm2, bm2, out);
}

// Round 8
// 197.595 us; speedup vs baseline: 2.6729x; 1.2786x over previous
//
#include <hip/hip_runtime.h>
#include <hip/hip_fp16.h>

// EtaGNN: 2x SAGE-conv (mean agg) + factorized MLP link predictor.
// Strategy: project-then-aggregate (linearity of mean), CSR gather (no f32 atomics),
// factorized query head (A[u]+B[v]+t*wt).
// R1: register-light dual_gemm (R0 spilled at 256 VGPR).
// R2: X tile in LDS, agg/query 16-lane float4 groups.
// R3: GEMM v4 - W via prefetched global float4, 64 rows/block; Wm1 pre-split.
// R4: binned fill REGRESSED 5x (atomics over 391 global counters -> cross-XCD
//     contention). Lesson: few-counter global atomics are poison.
// R5: fp16 storage for gathered buffers (rows 256B->128B), f32 accumulate.
// R6: GEMM v5 (2col/lane) REGRESSED (compiler dropped W prefetch, VGPR 48,
//     L2 latency serialized). CSR build atomic-free (worked, kept).
// R7: GEMM -> fp16 MFMA (16x16x32, f32 acc). No LDS, no barriers; A and B frags
//     are natural 32B contiguous loads (out = in @ W.T). k-mapping is
//     permutation-safe (same bijection used for A and B); C/D layout HW-verified.

constexpr int NN = 50000;   // nodes
constexpr int NE = 800000;  // edges
constexpr int NQ = 400000;  // queries
constexpr int NBUCKET = (NN + 127) >> 7;       // 391 buckets of 128 nodes
constexpr int EPB = 4096;                      // edges per scatter block
constexpr int NBLK_S = (NE + EPB - 1) / EPB;   // 196 scatter blocks

// ---------------- CSR build (atomic-free binned sort) ----------------
__global__ __launch_bounds__(256) void hist_kernel(const int* __restrict__ dst,
                                                   int* __restrict__ hist) {
    __shared__ int h[NBUCKET];
    int t = threadIdx.x, blk = blockIdx.x;
    for (int k = t; k < NBUCKET; k += 256) h[k] = 0;
    __syncthreads();
    int base = blk * EPB;
#pragma unroll
    for (int i = 0; i < EPB / 256; ++i) {
        int e = base + t + i * 256;
        if (e < NE) atomicAdd(&h[dst[e] >> 7], 1);
    }
    __syncthreads();
    for (int k = t; k < NBUCKET; k += 256) hist[blk * NBUCKET + k] = h[k];
}

__global__ __launch_bounds__(512) void scan_hist_kernel(int* __restrict__ hist,
                                                        int* __restrict__ bucket_base) {
    __shared__ int sd[512];
    int k = threadIdx.x;
    int tot = 0;
    if (k < NBUCKET)
        for (int b = 0; b < NBLK_S; ++b) tot += hist[b * NBUCKET + k];
    sd[k] = tot; __syncthreads();
    for (int off = 1; off < 512; off <<= 1) {
        int v = sd[k];
        if (k >= off) v += sd[k - off];
        __syncthreads(); sd[k] = v; __syncthreads();
    }
    int base = sd[k] - tot;  // exclusive
    if (k <= NBUCKET) bucket_base[k] = base;
    if (k < NBUCKET) {
        int run = base;
        for (int b = 0; b < NBLK_S; ++b) {
            int h = hist[b * NBUCKET + k];
            hist[b * NBUCKET + k] = run;
            run += h;
        }
    }
}

__global__ __launch_bounds__(256) void scatter_kernel(const int* __restrict__ src,
                                                      const int* __restrict__ dst,
                                                      const int* __restrict__ hist,
                                                      unsigned* __restrict__ tmp) {
    __shared__ int cur[NBUCKET];
    int t = threadIdx.x, blk = blockIdx.x;
    for (int k = t; k < NBUCKET; k += 256) cur[k] = hist[blk * NBUCKET + k];
    __syncthreads();
    int base = blk * EPB;
#pragma unroll
    for (int i = 0; i < EPB / 256; ++i) {
        int e = base + t + i * 256;
        if (e < NE) {
            int d = dst[e];
            int p = atomicAdd(&cur[d >> 7], 1);
            tmp[p] = ((unsigned)(d & 127) << 16) | (unsigned)src[e];
        }
    }
}

__global__ __launch_bounds__(256) void bucket_count_kernel(const int* __restrict__ bucket_base,
                                                           const unsigned* __restrict__ tmp,
                                                           int* __restrict__ cnt) {
    __shared__ int c[128];
    int t = threadIdx.x, b = blockIdx.x;
    if (t < 128) c[t] = 0;
    __syncthreads();
    int s = bucket_base[b], e1 = bucket_base[b + 1];
    for (int i = s + t; i < e1; i += 256) atomicAdd(&c[tmp[i] >> 16], 1);
    __syncthreads();
    int node = (b << 7) + t;
    if (t < 128 && node < NN) cnt[node] = c[t];
}

constexpr int SCHUNK = 1024;
constexpr int SBLK = (NN + SCHUNK - 1) / SCHUNK;  // 49 blocks

__global__ void scan_sum_kernel(const int* __restrict__ cnt, int* __restrict__ bsum) {
    __shared__ int sd[256];
    int t = threadIdx.x;
    int base = blockIdx.x * SCHUNK;
    int s = 0;
#pragma unroll
    for (int j = 0; j < 4; ++j) {
        int i = base + t + j * 256;
        if (i < NN) s += cnt[i];
    }
    sd[t] = s; __syncthreads();
    for (int off = 128; off > 0; off >>= 1) {
        if (t < off) sd[t] += sd[t + off];
        __syncthreads();
    }
    if (t == 0) bsum[blockIdx.x] = sd[0];
}

__global__ void scan_block_kernel(int* bsum) {  // 1 wave, exclusive scan in place
    int t = threadIdx.x;
    int orig = (t < SBLK) ? bsum[t] : 0;
    int v = orig;
#pragma unroll
    for (int off = 1; off < 64; off <<= 1) {
        int w = __shfl_up(v, off);
        if (t >= off) v += w;
    }
    if (t < SBLK) bsum[t] = v - orig;
}

__global__ void scan_write_kernel(const int* __restrict__ bsum, int* __restrict__ row_start,
                                  const int* __restrict__ cnt) {
    __shared__ int wsum[4];
    int t = threadIdx.x, lane = t & 63, wid = t >> 6;
    int base = blockIdx.x * SCHUNK;
    int v[4]; int s = 0;
#pragma unroll
    for (int j = 0; j < 4; ++j) {
        int i = base + t * 4 + j;
        v[j] = (i < NN) ? cnt[i] : 0;
        s += v[j];
    }
    int orig = s;
#pragma unroll
    for (int off = 1; off < 64; off <<= 1) {
        int w = __shfl_up(s, off);
        if (lane >= off) s += w;
    }
    if (lane == 63) wsum[wid] = s;
    __syncthreads();
    int woff = 0;
    for (int w = 0; w < wid; ++w) woff += wsum[w];
    int excl = bsum[blockIdx.x] + woff + (s - orig);
#pragma unroll
    for (int j = 0; j < 4; ++j) {
        int i = base + t * 4 + j;
        if (i <= NN) {
            row_start[i] = excl;
            excl += (i < NN) ? v[j] : 0;
        }
    }
}

__global__ __launch_bounds__(256) void csr_fill_kernel(const int* __restrict__ row_start,
                                                       const unsigned* __restrict__ tmp,
                                                       int* __restrict__ csr_src) {
    __shared__ int cur[128];
    int b = blockIdx.x;
    int node_base = b << 7;
    int n_nodes = NN - node_base; if (n_nodes > 128) n_nodes = 128;
    int t = threadIdx.x;
    if (t < n_nodes) cur[t] = row_start[node_base + t];
    __syncthreads();
    int bstart = row_start[node_base];
    int bend = row_start[node_base + n_nodes];
    for (int e = bstart + t; e < bend; e += 256) {
        unsigned pk = tmp[e];
        int p = atomicAdd(&cur[pk >> 16], 1);
        csr_src[p] = (int)(pk & 0xFFFFu);
    }
}

// ---------------- Wm1 split: WmA[64][64], WmB[64][64], wt[64] ----------------
__global__ void prep_wm1_kernel(const float* __restrict__ Wm1, float* __restrict__ WmA,
                                float* __restrict__ WmB, float* __restrict__ wt) {
    int t = blockIdx.x * 256 + threadIdx.x;
    if (t < 64 * 64) {
        int c = t >> 6, k = t & 63;
        WmA[t] = Wm1[c * 129 + k];
        WmB[t] = Wm1[c * 129 + 64 + k];
    }
    if (t < 64) wt[t] = Wm1[t * 129 + 128];
}

// ---------------- dual MFMA GEMM: outA = in @ Wa.T, outB = in @ Wb.T (Cout=64) ----------
// fp16 MFMA 16x16x32, f32 accumulate. Wave = 16 rows x 64 cols; block = 4 waves = 64 rows.
// No LDS, no barriers. A-frag: 8 contiguous f32 of X row (lane&15 = row, lane>>4 = kgrp).
// B-frag: 8 contiguous f32 of W row (col = lane&15). Same (grp,elem)->k bijection for
// A and B => k-order is permutation-safe. C/D: col = lane&15, row = (lane>>4)*4 + i.
typedef _Float16 f16x8 __attribute__((ext_vector_type(8)));
typedef float f32x4 __attribute__((ext_vector_type(4)));

template <typename T>
__device__ inline void store_conv(T* p, float v);
template <> __device__ inline void store_conv<float>(float* p, float v) { *p = v; }
template <> __device__ inline void store_conv<__half>(__half* p, float v) { *p = __float2half(v); }

__device__ inline f16x8 cvt8(float4 a, float4 b) {
    f16x8 r;
    r[0] = (_Float16)a.x; r[1] = (_Float16)a.y; r[2] = (_Float16)a.z; r[3] = (_Float16)a.w;
    r[4] = (_Float16)b.x; r[5] = (_Float16)b.y; r[6] = (_Float16)b.z; r[7] = (_Float16)b.w;
    return r;
}

template <int K, typename TA, typename TB>
__global__ __launch_bounds__(256) void dual_gemm_mfma(
    const float* __restrict__ in,
    const float* __restrict__ Wa, const float* __restrict__ Wb,
    TA* __restrict__ outA, TB* __restrict__ outB) {
    int t = threadIdx.x;
    int lane = t & 63, w = t >> 6;
    int r0 = blockIdx.x * 64 + w * 16;
    int rl = lane & 15, kg = lane >> 4;
    int gr = r0 + rl; if (gr >= NN) gr = NN - 1;  // clamp; stores guarded
    const float* arow = in + (size_t)gr * K + kg * 8;
    const float* warow = Wa + (size_t)rl * K + kg * 8;  // + ct*16*K per col tile
    const float* wbrow = Wb + (size_t)rl * K + kg * 8;
    f32x4 accA[4], accB[4];
#pragma unroll
    for (int ct = 0; ct < 4; ++ct) {
        accA[ct] = (f32x4){0.f, 0.f, 0.f, 0.f};
        accB[ct] = (f32x4){0.f, 0.f, 0.f, 0.f};
    }
    for (int ks = 0; ks < K; ks += 32) {
        float4 a0 = *(const float4*)(arow + ks);
        float4 a1 = *(const float4*)(arow + ks + 4);
        f16x8 af = cvt8(a0, a1);
#pragma unroll
        for (int ct = 0; ct < 4; ++ct) {
            const float* wa = warow + (size_t)ct * 16 * K + ks;
            const float* wb = wbrow + (size_t)ct * 16 * K + ks;
            float4 wa0 = *(const float4*)(wa);
            float4 wa1 = *(const float4*)(wa + 4);
            float4 wb0 = *(const float4*)(wb);
            float4 wb1 = *(const float4*)(wb + 4);
            f16x8 bfA = cvt8(wa0, wa1);
            f16x8 bfB = cvt8(wb0, wb1);
            accA[ct] = __builtin_amdgcn_mfma_f32_16x16x32_f16(af, bfA, accA[ct], 0, 0, 0);
            accB[ct] = __builtin_amdgcn_mfma_f32_16x16x32_f16(af, bfB, accB[ct], 0, 0, 0);
        }
    }
#pragma unroll
    for (int ct = 0; ct < 4; ++ct) {
#pragma unroll
        for (int i = 0; i < 4; ++i) {
            int row = r0 + kg * 4 + i;
            if (row < NN) {
                store_conv<TA>(&outA[(size_t)row * 64 + ct * 16 + rl], accA[ct][i]);
                store_conv<TB>(&outB[(size_t)row * 64 + ct * 16 + rl], accB[ct][i]);
            }
        }
    }
}

__device__ inline float2 u2f2(unsigned u) {
    __half2 h = *reinterpret_cast<__half2*>(&u);
    return __half22float2(h);
}

// ---------------- aggregation: out = relu(sum(p[src])/max(deg,1) + bias + selfp) ----------------
// p is fp16 rows (128B); 16 lanes per node (uint2 = 4 halves/lane), f32 accumulate.
__global__ __launch_bounds__(256) void agg_kernel(
    const __half* __restrict__ p, const float* __restrict__ selfp,
    const float* __restrict__ bias, const int* __restrict__ row_start,
    const int* __restrict__ csr_src, float* __restrict__ out) {
    int node = blockIdx.x * 16 + (threadIdx.x >> 4);
    int sub = threadIdx.x & 15;
    if (node >= NN) return;
    const uint2* p2 = (const uint2*)p;
    int s0 = row_start[node], s1 = row_start[node + 1];
    float4 acc = make_float4(0.f, 0.f, 0.f, 0.f);
    int e = s0;
    for (; e + 4 <= s1; e += 4) {
        int i0 = csr_src[e + 0], i1 = csr_src[e + 1];
        int i2 = csr_src[e + 2], i3 = csr_src[e + 3];
        uint2 a = p2[(size_t)i0 * 16 + sub];
        uint2 b = p2[(size_t)i1 * 16 + sub];
        uint2 cc = p2[(size_t)i2 * 16 + sub];
        uint2 d = p2[(size_t)i3 * 16 + sub];
        float2 a0 = u2f2(a.x), a1 = u2f2(a.y);
        float2 b0 = u2f2(b.x), b1 = u2f2(b.y);
        float2 c0 = u2f2(cc.x), c1 = u2f2(cc.y);
        float2 d0 = u2f2(d.x), d1 = u2f2(d.y);
        acc.x += (a0.x + b0.x) + (c0.x + d0.x);
        acc.y += (a0.y + b0.y) + (c0.y + d0.y);
        acc.z += (a1.x + b1.x) + (c1.x + d1.x);
        acc.w += (a1.y + b1.y) + (c1.y + d1.y);
    }
    for (; e < s1; ++e) {
        int s = csr_src[e];
        uint2 a = p2[(size_t)s * 16 + sub];
        float2 a0 = u2f2(a.x), a1 = u2f2(a.y);
        acc.x += a0.x; acc.y += a0.y; acc.z += a1.x; acc.w += a1.y;
    }
    float inv = 1.f / fmaxf((float)(s1 - s0), 1.f);
    float4 self = ((const float4*)selfp)[(size_t)node * 16 + sub];
    float4 bs = ((const float4*)bias)[sub];
    float4 r;
    r.x = fmaxf(fmaf(acc.x, inv, bs.x + self.x), 0.f);
    r.y = fmaxf(fmaf(acc.y, inv, bs.y + self.y), 0.f);
    r.z = fmaxf(fmaf(acc.z, inv, bs.z + self.z), 0.f);
    r.w = fmaxf(fmaf(acc.w, inv, bs.w + self.w), 0.f);
    ((float4*)out)[(size_t)node * 16 + sub] = r;
}

// ---------------- query head: out = relu(A[u]+B[v]+t*wt+bm1) . Wm2 + bm2 ----------------
// A,B fp16 rows (128B); grid-stride; 16 lanes per query (4 halves/lane), f32 math.
__global__ __launch_bounds__(256) void query_kernel(
    const int* __restrict__ uv, const float* __restrict__ tf,
    const __half* __restrict__ A, const __half* __restrict__ B,
    const float* __restrict__ wt, const float* __restrict__ bm1,
    const float* __restrict__ Wm2, const float* __restrict__ bm2,
    float* __restrict__ out) {
    int sub = threadIdx.x & 15;
    int gidx = (blockIdx.x * 256 + threadIdx.x) >> 4;
    int ngroups = (gridDim.x * 256) >> 4;
    const uint2* A2 = (const uint2*)A;
    const uint2* B2 = (const uint2*)B;
    const int2* uv2 = (const int2*)uv;
    float4 wt4 = ((const float4*)wt)[sub];
    float4 bm14 = ((const float4*)bm1)[sub];
    float4 wm24 = ((const float4*)Wm2)[sub];
    float bm2s = bm2[0];
#pragma unroll 2
    for (int q = gidx; q < NQ; q += ngroups) {
        int2 uvq = uv2[q];
        float t = tf[q];
        uint2 au = A2[(size_t)uvq.x * 16 + sub];
        uint2 bv = B2[(size_t)uvq.y * 16 + sub];
        float2 a0 = u2f2(au.x), a1 = u2f2(au.y);
        float2 b0 = u2f2(bv.x), b1 = u2f2(bv.y);
        float zx = fmaxf(a0.x + b0.x + t * wt4.x + bm14.x, 0.f) * wm24.x;
        float zy = fmaxf(a0.y + b0.y + t * wt4.y + bm14.y, 0.f) * wm24.y;
        float zz = fmaxf(a1.x + b1.x + t * wt4.z + bm14.z, 0.f) * wm24.z;
        float zw = fmaxf(a1.y + b1.y + t * wt4.w + bm14.w, 0.f) * wm24.w;
        float s = (zx + zy) + (zz + zw);
        s += __shfl_down(s, 8, 16);
        s += __shfl_down(s, 4, 16);
        s += __shfl_down(s, 2, 16);
        s += __shfl_down(s, 1, 16);
        if (sub == 0) out[q] = s + bm2s;
    }
}

extern "C" void kernel_launch(void* const* d_in, const int* in_sizes, int n_in,
                              void* d_out, int out_size, void* d_ws, size_t ws_size,
                              hipStream_t stream) {
    const float* x   = (const float*)d_in[0];
    const int*   ei  = (const int*)d_in[1];
    const int*   uv  = (const int*)d_in[2];
    const float* tf  = (const float*)d_in[3];
    const float* W1l = (const float*)d_in[4];
    const float* b1  = (const float*)d_in[5];
    const float* W1r = (const float*)d_in[6];
    const float* W2l = (const float*)d_in[7];
    const float* b2  = (const float*)d_in[8];
    const float* W2r = (const float*)d_in[9];
    const float* Wm1 = (const float*)d_in[10];
    const float* bm1 = (const float*)d_in[11];
    const float* Wm2 = (const float*)d_in[12];
    const float* bm2 = (const float*)d_in[13];
    float* out = (float*)d_out;

    char* ws = (char*)d_ws;
    size_t off = 0;
    auto take = [&](size_t bytes) -> void* {
        void* p = ws + off;
        off = (off + bytes + 255) & ~(size_t)255;
        return p;
    };
    int* row_start = (int*)take((NN + 1) * sizeof(int));
    int* cnt       = (int*)take((size_t)NN * sizeof(int));
    int* csr_src   = (int*)take((size_t)NE * sizeof(int));
    unsigned* tmp  = (unsigned*)take((size_t)NE * sizeof(unsigned));
    int* hist      = (int*)take((size_t)NBLK_S * NBUCKET * sizeof(int));
    int* bucket_base = (int*)take((NBUCKET + 1) * sizeof(int));
    int* bsum      = (int*)take(64 * sizeof(int));
    float* WmA = (float*)take(64 * 64 * sizeof(float));
    float* WmB = (float*)take(64 * 64 * sizeof(float));
    float* wt  = (float*)take(64 * sizeof(float));
    __half* ph   = (__half*)take((size_t)NN * 64 * sizeof(__half));  // neighbor proj / A
    __half* ph2  = (__half*)take((size_t)NN * 64 * sizeof(__half));  // B
    float* buf1 = (float*)take((size_t)NN * 64 * sizeof(float));     // self proj
    float* buf2 = (float*)take((size_t)NN * 64 * sizeof(float));     // layer output
    (void)in_sizes; (void)n_in; (void)out_size; (void)ws_size;

    const int* esrc = ei;
    const int* edst = ei + NE;

    // CSR build: histogram -> offsets -> scatter -> per-bucket count -> scan -> fill
    hist_kernel<<<NBLK_S, 256, 0, stream>>>(edst, hist);
    scan_hist_kernel<<<1, 512, 0, stream>>>(hist, bucket_base);
    scatter_kernel<<<NBLK_S, 256, 0, stream>>>(esrc, edst, hist, tmp);
    bucket_count_kernel<<<NBUCKET, 256, 0, stream>>>(bucket_base, tmp, cnt);
    scan_sum_kernel<<<SBLK, 256, 0, stream>>>(cnt, bsum);
    scan_block_kernel<<<1, 64, 0, stream>>>(bsum);
    scan_write_kernel<<<SBLK, 256, 0, stream>>>(bsum, row_start, cnt);
    csr_fill_kernel<<<NBUCKET, 256, 0, stream>>>(row_start, tmp, csr_src);
    prep_wm1_kernel<<<16, 256, 0, stream>>>(Wm1, WmA, WmB, wt);

    // Layer 1: p1 = x@W1l.T (fp16 ph), xr = x@W1r.T (f32 buf1); h1 = relu(mean+b1+xr) (buf2)
    dual_gemm_mfma<128, __half, float><<<(NN + 63) / 64, 256, 0, stream>>>(x, W1l, W1r, ph, buf1);
    agg_kernel<<<(NN + 15) / 16, 256, 0, stream>>>(ph, buf1, b1, row_start, csr_src, buf2);
    // Layer 2
    dual_gemm_mfma<64, __half, float><<<(NN + 63) / 64, 256, 0, stream>>>(buf2, W2l, W2r, ph, buf1);
    agg_kernel<<<(NN + 15) / 16, 256, 0, stream>>>(ph, buf1, b2, row_start, csr_src, buf2);
    // MLP factorization: A = h2@WmA.T (fp16 ph), B = h2@WmB.T (fp16 ph2)
    dual_gemm_mfma<64, __half, __half><<<(NN + 63) / 64, 256, 0, stream>>>(buf2, WmA, WmB, ph, ph2);
    // Per-query head
    query_kernel<<<2048, 256, 0, stream>>>(uv, tf, ph, ph2, wt, bm1, Wm2, bm2, out);
}

// Round 9
// 181.744 us; speedup vs baseline: 2.9060x; 1.0872x over previous
//
#include <hip/hip_runtime.h>
#include <hip/hip_fp16.h>

// EtaGNN: 2x SAGE-conv (mean agg) + factorized MLP link predictor.
// Strategy: project-then-aggregate (linearity of mean), CSR gather (no f32 atomics),
// factorized query head (A[u]+B[v]+t*wt).
// R1-R3: register-light GEMM evolution; Wm1 pre-split.
// R4: lesson - few-counter global atomics are poison (cross-XCD contention).
// R5: fp16 storage for gathered buffers (rows 256B->128B), f32 accumulate.
// R6: CSR build atomic-free (binned sort via per-block LDS histograms).
// R7: GEMM -> fp16 MFMA 16x16x32, f32 acc, no LDS/barriers. Worked.
// R8: fuse agg+gemm per layer (LDS h-tile, kills buf2 round trip + 2 launches);
//     CSR: parallel per-bucket wave scans replace 1-block serial scan; fused
//     count+scan+row_start+fill kernel. 15 -> 10 launches.

constexpr int NN = 50000;   // nodes
constexpr int NE = 800000;  // edges
constexpr int NQ = 400000;  // queries
constexpr int NBUCKET = (NN + 127) >> 7;       // 391 buckets of 128 nodes
constexpr int EPB = 4096;                      // edges per scatter block
constexpr int NBLK_S = (NE + EPB - 1) / EPB;   // 196 scatter blocks

// ---------------- CSR build (atomic-free binned sort) ----------------
// (a) per-block bucket histogram, row-major hist[b][k]
__global__ __launch_bounds__(256) void hist_kernel(const int* __restrict__ dst,
                                                   int* __restrict__ hist) {
    __shared__ int h[NBUCKET];
    int t = threadIdx.x, blk = blockIdx.x;
    for (int k = t; k < NBUCKET; k += 256) h[k] = 0;
    __syncthreads();
    int base = blk * EPB;
#pragma unroll
    for (int i = 0; i < EPB / 256; ++i) {
        int e = base + t + i * 256;
        if (e < NE) atomicAdd(&h[dst[e] >> 7], 1);
    }
    __syncthreads();
    for (int k = t; k < NBUCKET; k += 256) hist[blk * NBUCKET + k] = h[k];
}

// (b) per-bucket totals: one wave per bucket
__global__ __launch_bounds__(256) void scanA_kernel(const int* __restrict__ hist,
                                                    int* __restrict__ total) {
    int w = threadIdx.x >> 6, lane = threadIdx.x & 63;
    int k = blockIdx.x * 4 + w;
    if (k >= NBUCKET) return;
    int s = 0;
#pragma unroll
    for (int c = 0; c < 4; ++c) {
        int b = c * 64 + lane;
        if (b < NBLK_S) s += hist[(size_t)b * NBUCKET + k];
    }
#pragma unroll
    for (int off = 32; off > 0; off >>= 1) s += __shfl_down(s, off);
    if (lane == 0) total[k] = s;
}

// (c) block 0: exclusive scan of 391 totals -> bucket_base; block 1: Wm1 split
__global__ __launch_bounds__(512) void scanB_prep_kernel(
    const int* __restrict__ total, int* __restrict__ bucket_base,
    const float* __restrict__ Wm1, float* __restrict__ WmA,
    float* __restrict__ WmB, float* __restrict__ wt) {
    if (blockIdx.x == 0) {
        __shared__ int sd[512];
        int k = threadIdx.x;
        int v0 = (k < NBUCKET) ? total[k] : 0;
        sd[k] = v0; __syncthreads();
        for (int off = 1; off < 512; off <<= 1) {
            int v = sd[k];
            if (k >= off) v += sd[k - off];
            __syncthreads(); sd[k] = v; __syncthreads();
        }
        if (k <= NBUCKET) bucket_base[k] = sd[k] - v0;  // exclusive
    } else {
        int t = threadIdx.x;
        for (int idx = t; idx < 64 * 64; idx += 512) {
            int c = idx >> 6, k = idx & 63;
            WmA[idx] = Wm1[c * 129 + k];
            WmB[idx] = Wm1[c * 129 + 64 + k];
        }
        if (t < 64) wt[t] = Wm1[t * 129 + 128];
    }
}

// (d) per-bucket offsets across scatter blocks: one wave per bucket
__global__ __launch_bounds__(256) void scanC_kernel(int* __restrict__ hist,
                                                    const int* __restrict__ bucket_base) {
    int w = threadIdx.x >> 6, lane = threadIdx.x & 63;
    int k = blockIdx.x * 4 + w;
    if (k >= NBUCKET) return;
    int run = bucket_base[k];
#pragma unroll
    for (int c = 0; c < 4; ++c) {
        int b = c * 64 + lane;
        int v = (b < NBLK_S) ? hist[(size_t)b * NBUCKET + k] : 0;
        int orig = v;
#pragma unroll
        for (int off = 1; off < 64; off <<= 1) {
            int u = __shfl_up(v, off);
            if (lane >= off) v += u;
        }
        if (b < NBLK_S) hist[(size_t)b * NBUCKET + k] = run + v - orig;
        run += __shfl(v, 63);
    }
}

// (e) scatter edges into bucket-ordered tmp via per-block LDS cursors
__global__ __launch_bounds__(256) void scatter_kernel(const int* __restrict__ src,
                                                      const int* __restrict__ dst,
                                                      const int* __restrict__ hist,
                                                      unsigned* __restrict__ tmp) {
    __shared__ int cur[NBUCKET];
    int t = threadIdx.x, blk = blockIdx.x;
    for (int k = t; k < NBUCKET; k += 256) cur[k] = hist[blk * NBUCKET + k];
    __syncthreads();
    int base = blk * EPB;
#pragma unroll
    for (int i = 0; i < EPB / 256; ++i) {
        int e = base + t + i * 256;
        if (e < NE) {
            int d = dst[e];
            int p = atomicAdd(&cur[d >> 7], 1);
            tmp[p] = ((unsigned)(d & 127) << 16) | (unsigned)src[e];
        }
    }
}

// (f) per-bucket: count -> 128-scan -> row_start + cursors -> fill
__global__ __launch_bounds__(256) void csr_fill_fused(const int* __restrict__ bucket_base,
                                                      const unsigned* __restrict__ tmp,
                                                      int* __restrict__ csr_src,
                                                      int* __restrict__ row_start) {
    __shared__ int c[128];
    __shared__ int cur[128];
    __shared__ int wtot;
    int b = blockIdx.x;
    int node_base = b << 7;
    int t = threadIdx.x, lane = t & 63, wv = t >> 6;
    if (t < 128) c[t] = 0;
    __syncthreads();
    int s = bucket_base[b], e1 = bucket_base[b + 1];
    for (int i = s + t; i < e1; i += 256) atomicAdd(&c[tmp[i] >> 16], 1);
    __syncthreads();
    // exclusive scan of c[0..127] using waves 0,1
    int own = (t < 128) ? c[t] : 0;
    int v = own;
#pragma unroll
    for (int off = 1; off < 64; off <<= 1) {
        int u = __shfl_up(v, off);
        if (lane >= off) v += u;
    }
    if (t < 128 && lane == 63 && wv == 0) wtot = v;
    __syncthreads();
    if (t < 128) {
        int excl = v - own + ((wv == 1) ? wtot : 0);
        int pos = s + excl;
        cur[t] = pos;
        int node = node_base + t;
        if (node < NN) row_start[node] = pos;
    }
    if (b == NBUCKET - 1 && t == 0) row_start[NN] = e1;
    __syncthreads();
    for (int i = s + t; i < e1; i += 256) {
        unsigned pk = tmp[i];
        int p = atomicAdd(&cur[pk >> 16], 1);
        csr_src[p] = (int)(pk & 0xFFFFu);
    }
}

// ---------------- MFMA helpers ----------------
typedef _Float16 f16x8 __attribute__((ext_vector_type(8)));
typedef float f32x4 __attribute__((ext_vector_type(4)));

template <typename T>
__device__ inline void store_conv(T* p, float v);
template <> __device__ inline void store_conv<float>(float* p, float v) { *p = v; }
template <> __device__ inline void store_conv<__half>(__half* p, float v) { *p = __float2half(v); }

__device__ inline f16x8 cvt8(float4 a, float4 b) {
    f16x8 r;
    r[0] = (_Float16)a.x; r[1] = (_Float16)a.y; r[2] = (_Float16)a.z; r[3] = (_Float16)a.w;
    r[4] = (_Float16)b.x; r[5] = (_Float16)b.y; r[6] = (_Float16)b.z; r[7] = (_Float16)b.w;
    return r;
}

// ---------------- dual MFMA GEMM (layer 1, K=128, input = x) ----------------
// Wave = 16 rows x 64 cols; block = 4 waves = 64 rows. No LDS, no barriers.
// A-frag/B-frag: same (grp,elem)->k bijection => permutation-safe k order.
template <int K, typename TA, typename TB>
__global__ __launch_bounds__(256) void dual_gemm_mfma(
    const float* __restrict__ in,
    const float* __restrict__ Wa, const float* __restrict__ Wb,
    TA* __restrict__ outA, TB* __restrict__ outB) {
    int t = threadIdx.x;
    int lane = t & 63, w = t >> 6;
    int r0 = blockIdx.x * 64 + w * 16;
    int rl = lane & 15, kg = lane >> 4;
    int gr = r0 + rl; if (gr >= NN) gr = NN - 1;  // clamp; stores guarded
    const float* arow = in + (size_t)gr * K + kg * 8;
    const float* warow = Wa + (size_t)rl * K + kg * 8;
    const float* wbrow = Wb + (size_t)rl * K + kg * 8;
    f32x4 accA[4], accB[4];
#pragma unroll
    for (int ct = 0; ct < 4; ++ct) {
        accA[ct] = (f32x4){0.f, 0.f, 0.f, 0.f};
        accB[ct] = (f32x4){0.f, 0.f, 0.f, 0.f};
    }
    for (int ks = 0; ks < K; ks += 32) {
        float4 a0 = *(const float4*)(arow + ks);
        float4 a1 = *(const float4*)(arow + ks + 4);
        f16x8 af = cvt8(a0, a1);
#pragma unroll
        for (int ct = 0; ct < 4; ++ct) {
            const float* wa = warow + (size_t)ct * 16 * K + ks;
            const float* wb = wbrow + (size_t)ct * 16 * K + ks;
            f16x8 bfA = cvt8(*(const float4*)(wa), *(const float4*)(wa + 4));
            f16x8 bfB = cvt8(*(const float4*)(wb), *(const float4*)(wb + 4));
            accA[ct] = __builtin_amdgcn_mfma_f32_16x16x32_f16(af, bfA, accA[ct], 0, 0, 0);
            accB[ct] = __builtin_amdgcn_mfma_f32_16x16x32_f16(af, bfB, accB[ct], 0, 0, 0);
        }
    }
#pragma unroll
    for (int ct = 0; ct < 4; ++ct) {
#pragma unroll
        for (int i = 0; i < 4; ++i) {
            int row = r0 + kg * 4 + i;
            if (row < NN) {
                store_conv<TA>(&outA[(size_t)row * 64 + ct * 16 + rl], accA[ct][i]);
                store_conv<TB>(&outB[(size_t)row * 64 + ct * 16 + rl], accB[ct][i]);
            }
        }
    }
}

__device__ inline float2 u2f2(unsigned u) {
    __half2 h = *reinterpret_cast<__half2*>(&u);
    return __half22float2(h);
}

// ---------------- fused agg + dual MFMA GEMM (layers 2,3; K=64) ----------------
// Phase 1: 16-lane groups aggregate 64 nodes -> h tile in LDS (f32, identical math
// to the old agg_kernel). Phase 2: MFMA projection h @ Wa.T / Wb.T from LDS.
template <typename TA, typename TB>
__global__ __launch_bounds__(256) void fused_agg_gemm(
    const __half* __restrict__ p, const float* __restrict__ selfp,
    const float* __restrict__ bias, const int* __restrict__ row_start,
    const int* __restrict__ csr_src,
    const float* __restrict__ Wa, const float* __restrict__ Wb,
    TA* __restrict__ outA, TB* __restrict__ outB) {
    __shared__ float Xs[64][68];  // padded: 272B rows, 16B-aligned
    int t = threadIdx.x;
    int rbase = blockIdx.x * 64;
    {
        int grp = t >> 4, sub = t & 15;
        const uint2* p2 = (const uint2*)p;
#pragma unroll
        for (int pass = 0; pass < 4; ++pass) {
            int nl = pass * 16 + grp;
            int node = rbase + nl;
            float4 r = make_float4(0.f, 0.f, 0.f, 0.f);
            if (node < NN) {
                int s0 = row_start[node], s1 = row_start[node + 1];
                float4 acc = make_float4(0.f, 0.f, 0.f, 0.f);
                int e = s0;
                for (; e + 4 <= s1; e += 4) {
                    int i0 = csr_src[e + 0], i1 = csr_src[e + 1];
                    int i2 = csr_src[e + 2], i3 = csr_src[e + 3];
                    uint2 a = p2[(size_t)i0 * 16 + sub];
                    uint2 b = p2[(size_t)i1 * 16 + sub];
                    uint2 cc = p2[(size_t)i2 * 16 + sub];
                    uint2 d = p2[(size_t)i3 * 16 + sub];
                    float2 a0 = u2f2(a.x), a1 = u2f2(a.y);
                    float2 b0 = u2f2(b.x), b1 = u2f2(b.y);
                    float2 c0 = u2f2(cc.x), c1 = u2f2(cc.y);
                    float2 d0 = u2f2(d.x), d1 = u2f2(d.y);
                    acc.x += (a0.x + b0.x) + (c0.x + d0.x);
                    acc.y += (a0.y + b0.y) + (c0.y + d0.y);
                    acc.z += (a1.x + b1.x) + (c1.x + d1.x);
                    acc.w += (a1.y + b1.y) + (c1.y + d1.y);
                }
                for (; e < s1; ++e) {
                    int sI = csr_src[e];
                    uint2 a = p2[(size_t)sI * 16 + sub];
                    float2 a0 = u2f2(a.x), a1 = u2f2(a.y);
                    acc.x += a0.x; acc.y += a0.y; acc.z += a1.x; acc.w += a1.y;
                }
                float inv = 1.f / fmaxf((float)(s1 - s0), 1.f);
                float4 self = ((const float4*)selfp)[(size_t)node * 16 + sub];
                float4 bs = ((const float4*)bias)[sub];
                r.x = fmaxf(fmaf(acc.x, inv, bs.x + self.x), 0.f);
                r.y = fmaxf(fmaf(acc.y, inv, bs.y + self.y), 0.f);
                r.z = fmaxf(fmaf(acc.z, inv, bs.z + self.z), 0.f);
                r.w = fmaxf(fmaf(acc.w, inv, bs.w + self.w), 0.f);
            }
            *(float4*)&Xs[nl][sub * 4] = r;
        }
    }
    __syncthreads();
    int lane = t & 63, w = t >> 6;
    int rl = lane & 15, kg = lane >> 4;
    int lrow = w * 16 + rl;
    const float* warow = Wa + (size_t)rl * 64 + kg * 8;
    const float* wbrow = Wb + (size_t)rl * 64 + kg * 8;
    f32x4 accA[4], accB[4];
#pragma unroll
    for (int ct = 0; ct < 4; ++ct) {
        accA[ct] = (f32x4){0.f, 0.f, 0.f, 0.f};
        accB[ct] = (f32x4){0.f, 0.f, 0.f, 0.f};
    }
#pragma unroll
    for (int ks = 0; ks < 64; ks += 32) {
        float4 a0 = *(const float4*)&Xs[lrow][kg * 8 + ks];
        float4 a1 = *(const float4*)&Xs[lrow][kg * 8 + ks + 4];
        f16x8 af = cvt8(a0, a1);
#pragma unroll
        for (int ct = 0; ct < 4; ++ct) {
            const float* wa = warow + (size_t)ct * 16 * 64 + ks;
            const float* wb = wbrow + (size_t)ct * 16 * 64 + ks;
            f16x8 bfA = cvt8(*(const float4*)(wa), *(const float4*)(wa + 4));
            f16x8 bfB = cvt8(*(const float4*)(wb), *(const float4*)(wb + 4));
            accA[ct] = __builtin_amdgcn_mfma_f32_16x16x32_f16(af, bfA, accA[ct], 0, 0, 0);
            accB[ct] = __builtin_amdgcn_mfma_f32_16x16x32_f16(af, bfB, accB[ct], 0, 0, 0);
        }
    }
    int r0 = rbase + w * 16;
#pragma unroll
    for (int ct = 0; ct < 4; ++ct) {
#pragma unroll
        for (int i = 0; i < 4; ++i) {
            int row = r0 + kg * 4 + i;
            if (row < NN) {
                store_conv<TA>(&outA[(size_t)row * 64 + ct * 16 + rl], accA[ct][i]);
                store_conv<TB>(&outB[(size_t)row * 64 + ct * 16 + rl], accB[ct][i]);
            }
        }
    }
}

// ---------------- query head: out = relu(A[u]+B[v]+t*wt+bm1) . Wm2 + bm2 ----------------
__global__ __launch_bounds__(256) void query_kernel(
    const int* __restrict__ uv, const float* __restrict__ tf,
    const __half* __restrict__ A, const __half* __restrict__ B,
    const float* __restrict__ wt, const float* __restrict__ bm1,
    const float* __restrict__ Wm2, const float* __restrict__ bm2,
    float* __restrict__ out) {
    int sub = threadIdx.x & 15;
    int gidx = (blockIdx.x * 256 + threadIdx.x) >> 4;
    int ngroups = (gridDim.x * 256) >> 4;
    const uint2* A2 = (const uint2*)A;
    const uint2* B2 = (const uint2*)B;
    const int2* uv2 = (const int2*)uv;
    float4 wt4 = ((const float4*)wt)[sub];
    float4 bm14 = ((const float4*)bm1)[sub];
    float4 wm24 = ((const float4*)Wm2)[sub];
    float bm2s = bm2[0];
#pragma unroll 2
    for (int q = gidx; q < NQ; q += ngroups) {
        int2 uvq = uv2[q];
        float t = tf[q];
        uint2 au = A2[(size_t)uvq.x * 16 + sub];
        uint2 bv = B2[(size_t)uvq.y * 16 + sub];
        float2 a0 = u2f2(au.x), a1 = u2f2(au.y);
        float2 b0 = u2f2(bv.x), b1 = u2f2(bv.y);
        float zx = fmaxf(a0.x + b0.x + t * wt4.x + bm14.x, 0.f) * wm24.x;
        float zy = fmaxf(a0.y + b0.y + t * wt4.y + bm14.y, 0.f) * wm24.y;
        float zz = fmaxf(a1.x + b1.x + t * wt4.z + bm14.z, 0.f) * wm24.z;
        float zw = fmaxf(a1.y + b1.y + t * wt4.w + bm14.w, 0.f) * wm24.w;
        float s = (zx + zy) + (zz + zw);
        s += __shfl_down(s, 8, 16);
        s += __shfl_down(s, 4, 16);
        s += __shfl_down(s, 2, 16);
        s += __shfl_down(s, 1, 16);
        if (sub == 0) out[q] = s + bm2s;
    }
}

extern "C" void kernel_launch(void* const* d_in, const int* in_sizes, int n_in,
                              void* d_out, int out_size, void* d_ws, size_t ws_size,
                              hipStream_t stream) {
    const float* x   = (const float*)d_in[0];
    const int*   ei  = (const int*)d_in[1];
    const int*   uv  = (const int*)d_in[2];
    const float* tf  = (const float*)d_in[3];
    const float* W1l = (const float*)d_in[4];
    const float* b1  = (const float*)d_in[5];
    const float* W1r = (const float*)d_in[6];
    const float* W2l = (const float*)d_in[7];
    const float* b2  = (const float*)d_in[8];
    const float* W2r = (const float*)d_in[9];
    const float* Wm1 = (const float*)d_in[10];
    const float* bm1 = (const float*)d_in[11];
    const float* Wm2 = (const float*)d_in[12];
    const float* bm2 = (const float*)d_in[13];
    float* out = (float*)d_out;

    char* ws = (char*)d_ws;
    size_t off = 0;
    auto take = [&](size_t bytes) -> void* {
        void* p = ws + off;
        off = (off + bytes + 255) & ~(size_t)255;
        return p;
    };
    int* row_start = (int*)take((NN + 1) * sizeof(int));
    int* csr_src   = (int*)take((size_t)NE * sizeof(int));
    unsigned* tmp  = (unsigned*)take((size_t)NE * sizeof(unsigned));
    int* hist      = (int*)take((size_t)NBLK_S * NBUCKET * sizeof(int));
    int* total     = (int*)take((NBUCKET + 1) * sizeof(int));
    int* bucket_base = (int*)take((NBUCKET + 1) * sizeof(int));
    float* WmA = (float*)take(64 * 64 * sizeof(float));
    float* WmB = (float*)take(64 * 64 * sizeof(float));
    float* wt  = (float*)take(64 * sizeof(float));
    __half* bufA = (__half*)take((size_t)NN * 64 * sizeof(__half));  // p1 / A
    __half* bufC = (__half*)take((size_t)NN * 64 * sizeof(__half));  // p2
    __half* bufE = (__half*)take((size_t)NN * 64 * sizeof(__half));  // B
    float* bufB = (float*)take((size_t)NN * 64 * sizeof(float));     // s1
    float* bufD = (float*)take((size_t)NN * 64 * sizeof(float));     // s2
    (void)in_sizes; (void)n_in; (void)out_size; (void)ws_size;

    const int* esrc = ei;
    const int* edst = ei + NE;

    // CSR build: hist -> totals -> scan(+Wm1 prep) -> offsets -> scatter -> fused fill
    hist_kernel<<<NBLK_S, 256, 0, stream>>>(edst, hist);
    scanA_kernel<<<(NBUCKET + 3) / 4, 256, 0, stream>>>(hist, total);
    scanB_prep_kernel<<<2, 512, 0, stream>>>(total, bucket_base, Wm1, WmA, WmB, wt);
    scanC_kernel<<<(NBUCKET + 3) / 4, 256, 0, stream>>>(hist, bucket_base);
    scatter_kernel<<<NBLK_S, 256, 0, stream>>>(esrc, edst, hist, tmp);
    csr_fill_fused<<<NBUCKET, 256, 0, stream>>>(bucket_base, tmp, csr_src, row_start);

    // Layer 1: p1 = x@W1l.T (fp16 bufA), s1 = x@W1r.T (f32 bufB)
    dual_gemm_mfma<128, __half, float><<<(NN + 63) / 64, 256, 0, stream>>>(x, W1l, W1r, bufA, bufB);
    // Layer 2 fused: h1 = relu(mean(p1)+b1+s1); p2 = h1@W2l.T (bufC), s2 = h1@W2r.T (bufD)
    fused_agg_gemm<__half, float><<<(NN + 63) / 64, 256, 0, stream>>>(
        bufA, bufB, b1, row_start, csr_src, W2l, W2r, bufC, bufD);
    // Layer 3 fused: h2 = relu(mean(p2)+b2+s2); A = h2@WmA.T (bufA), B = h2@WmB.T (bufE)
    fused_agg_gemm<__half, __half><<<(NN + 63) / 64, 256, 0, stream>>>(
        bufC, bufD, b2, row_start, csr_src, WmA, WmB, bufA, bufE);
    // Per-query head
    query_kernel<<<2048, 256, 0, stream>>>(uv, tf, bufA, bufE, wt, bm1, Wm2, bm2, out);
}

// Round 10
// 165.514 us; speedup vs baseline: 3.1910x; 1.0981x over previous
//
#include <hip/hip_runtime.h>
#include <hip/hip_fp16.h>

// EtaGNN: 2x SAGE-conv (mean agg) + factorized MLP link predictor.
// Strategy: project-then-aggregate (linearity of mean), CSR gather (no f32 atomics),
// factorized query head (A[u]+B[v]+t*wt).
// R1-R3: register-light GEMM evolution; Wm1 pre-split.
// R4: lesson - few-counter global atomics are poison (cross-XCD contention).
// R5: fp16 storage for gathered buffers (rows 256B->128B), f32 accumulate.
// R6: CSR build atomic-free (binned sort via per-block LDS histograms).
// R7: GEMM -> fp16 MFMA 16x16x32, f32 acc, no LDS/barriers. Worked.
// R8: fused agg+gemm per layer; parallel CSR scans; 10 launches. Worked.
// R9: gather phases were latency-bound (VALU 14%, HBM 16%, occ 22%). 8-lane
//     uint4 groups + 8-deep unroll (2x gathers in flight, half the instrs);
//     fused blocks 128thr/32rows (grid 782->1563, finer balance); query same.

constexpr int NN = 50000;   // nodes
constexpr int NE = 800000;  // edges
constexpr int NQ = 400000;  // queries
constexpr int NBUCKET = (NN + 127) >> 7;       // 391 buckets of 128 nodes
constexpr int EPB = 4096;                      // edges per scatter block
constexpr int NBLK_S = (NE + EPB - 1) / EPB;   // 196 scatter blocks

// ---------------- CSR build (atomic-free binned sort) ----------------
__global__ __launch_bounds__(256) void hist_kernel(const int* __restrict__ dst,
                                                   int* __restrict__ hist) {
    __shared__ int h[NBUCKET];
    int t = threadIdx.x, blk = blockIdx.x;
    for (int k = t; k < NBUCKET; k += 256) h[k] = 0;
    __syncthreads();
    int base = blk * EPB;
#pragma unroll
    for (int i = 0; i < EPB / 256; ++i) {
        int e = base + t + i * 256;
        if (e < NE) atomicAdd(&h[dst[e] >> 7], 1);
    }
    __syncthreads();
    for (int k = t; k < NBUCKET; k += 256) hist[blk * NBUCKET + k] = h[k];
}

__global__ __launch_bounds__(256) void scanA_kernel(const int* __restrict__ hist,
                                                    int* __restrict__ total) {
    int w = threadIdx.x >> 6, lane = threadIdx.x & 63;
    int k = blockIdx.x * 4 + w;
    if (k >= NBUCKET) return;
    int s = 0;
#pragma unroll
    for (int c = 0; c < 4; ++c) {
        int b = c * 64 + lane;
        if (b < NBLK_S) s += hist[(size_t)b * NBUCKET + k];
    }
#pragma unroll
    for (int off = 32; off > 0; off >>= 1) s += __shfl_down(s, off);
    if (lane == 0) total[k] = s;
}

__global__ __launch_bounds__(512) void scanB_prep_kernel(
    const int* __restrict__ total, int* __restrict__ bucket_base,
    const float* __restrict__ Wm1, float* __restrict__ WmA,
    float* __restrict__ WmB, float* __restrict__ wt) {
    if (blockIdx.x == 0) {
        __shared__ int sd[512];
        int k = threadIdx.x;
        int v0 = (k < NBUCKET) ? total[k] : 0;
        sd[k] = v0; __syncthreads();
        for (int off = 1; off < 512; off <<= 1) {
            int v = sd[k];
            if (k >= off) v += sd[k - off];
            __syncthreads(); sd[k] = v; __syncthreads();
        }
        if (k <= NBUCKET) bucket_base[k] = sd[k] - v0;  // exclusive
    } else {
        int t = threadIdx.x;
        for (int idx = t; idx < 64 * 64; idx += 512) {
            int c = idx >> 6, k = idx & 63;
            WmA[idx] = Wm1[c * 129 + k];
            WmB[idx] = Wm1[c * 129 + 64 + k];
        }
        if (t < 64) wt[t] = Wm1[t * 129 + 128];
    }
}

__global__ __launch_bounds__(256) void scanC_kernel(int* __restrict__ hist,
                                                    const int* __restrict__ bucket_base) {
    int w = threadIdx.x >> 6, lane = threadIdx.x & 63;
    int k = blockIdx.x * 4 + w;
    if (k >= NBUCKET) return;
    int run = bucket_base[k];
#pragma unroll
    for (int c = 0; c < 4; ++c) {
        int b = c * 64 + lane;
        int v = (b < NBLK_S) ? hist[(size_t)b * NBUCKET + k] : 0;
        int orig = v;
#pragma unroll
        for (int off = 1; off < 64; off <<= 1) {
            int u = __shfl_up(v, off);
            if (lane >= off) v += u;
        }
        if (b < NBLK_S) hist[(size_t)b * NBUCKET + k] = run + v - orig;
        run += __shfl(v, 63);
    }
}

__global__ __launch_bounds__(256) void scatter_kernel(const int* __restrict__ src,
                                                      const int* __restrict__ dst,
                                                      const int* __restrict__ hist,
                                                      unsigned* __restrict__ tmp) {
    __shared__ int cur[NBUCKET];
    int t = threadIdx.x, blk = blockIdx.x;
    for (int k = t; k < NBUCKET; k += 256) cur[k] = hist[blk * NBUCKET + k];
    __syncthreads();
    int base = blk * EPB;
#pragma unroll
    for (int i = 0; i < EPB / 256; ++i) {
        int e = base + t + i * 256;
        if (e < NE) {
            int d = dst[e];
            int p = atomicAdd(&cur[d >> 7], 1);
            tmp[p] = ((unsigned)(d & 127) << 16) | (unsigned)src[e];
        }
    }
}

__global__ __launch_bounds__(256) void csr_fill_fused(const int* __restrict__ bucket_base,
                                                      const unsigned* __restrict__ tmp,
                                                      int* __restrict__ csr_src,
                                                      int* __restrict__ row_start) {
    __shared__ int c[128];
    __shared__ int cur[128];
    __shared__ int wtot;
    int b = blockIdx.x;
    int node_base = b << 7;
    int t = threadIdx.x, lane = t & 63, wv = t >> 6;
    if (t < 128) c[t] = 0;
    __syncthreads();
    int s = bucket_base[b], e1 = bucket_base[b + 1];
    for (int i = s + t; i < e1; i += 256) atomicAdd(&c[tmp[i] >> 16], 1);
    __syncthreads();
    int own = (t < 128) ? c[t] : 0;
    int v = own;
#pragma unroll
    for (int off = 1; off < 64; off <<= 1) {
        int u = __shfl_up(v, off);
        if (lane >= off) v += u;
    }
    if (t < 128 && lane == 63 && wv == 0) wtot = v;
    __syncthreads();
    if (t < 128) {
        int excl = v - own + ((wv == 1) ? wtot : 0);
        int pos = s + excl;
        cur[t] = pos;
        int node = node_base + t;
        if (node < NN) row_start[node] = pos;
    }
    if (b == NBUCKET - 1 && t == 0) row_start[NN] = e1;
    __syncthreads();
    for (int i = s + t; i < e1; i += 256) {
        unsigned pk = tmp[i];
        int p = atomicAdd(&cur[pk >> 16], 1);
        csr_src[p] = (int)(pk & 0xFFFFu);
    }
}

// ---------------- MFMA helpers ----------------
typedef _Float16 f16x8 __attribute__((ext_vector_type(8)));
typedef float f32x4 __attribute__((ext_vector_type(4)));

template <typename T>
__device__ inline void store_conv(T* p, float v);
template <> __device__ inline void store_conv<float>(float* p, float v) { *p = v; }
template <> __device__ inline void store_conv<__half>(__half* p, float v) { *p = __float2half(v); }

__device__ inline f16x8 cvt8(float4 a, float4 b) {
    f16x8 r;
    r[0] = (_Float16)a.x; r[1] = (_Float16)a.y; r[2] = (_Float16)a.z; r[3] = (_Float16)a.w;
    r[4] = (_Float16)b.x; r[5] = (_Float16)b.y; r[6] = (_Float16)b.z; r[7] = (_Float16)b.w;
    return r;
}

__device__ inline float2 u2f2(unsigned u) {
    __half2 h = *reinterpret_cast<__half2*>(&u);
    return __half22float2(h);
}

// ---------------- dual MFMA GEMM (layer 1, K=128, input = x) ----------------
template <int K, typename TA, typename TB>
__global__ __launch_bounds__(256) void dual_gemm_mfma(
    const float* __restrict__ in,
    const float* __restrict__ Wa, const float* __restrict__ Wb,
    TA* __restrict__ outA, TB* __restrict__ outB) {
    int t = threadIdx.x;
    int lane = t & 63, w = t >> 6;
    int r0 = blockIdx.x * 64 + w * 16;
    int rl = lane & 15, kg = lane >> 4;
    int gr = r0 + rl; if (gr >= NN) gr = NN - 1;  // clamp; stores guarded
    const float* arow = in + (size_t)gr * K + kg * 8;
    const float* warow = Wa + (size_t)rl * K + kg * 8;
    const float* wbrow = Wb + (size_t)rl * K + kg * 8;
    f32x4 accA[4], accB[4];
#pragma unroll
    for (int ct = 0; ct < 4; ++ct) {
        accA[ct] = (f32x4){0.f, 0.f, 0.f, 0.f};
        accB[ct] = (f32x4){0.f, 0.f, 0.f, 0.f};
    }
    for (int ks = 0; ks < K; ks += 32) {
        float4 a0 = *(const float4*)(arow + ks);
        float4 a1 = *(const float4*)(arow + ks + 4);
        f16x8 af = cvt8(a0, a1);
#pragma unroll
        for (int ct = 0; ct < 4; ++ct) {
            const float* wa = warow + (size_t)ct * 16 * K + ks;
            const float* wb = wbrow + (size_t)ct * 16 * K + ks;
            f16x8 bfA = cvt8(*(const float4*)(wa), *(const float4*)(wa + 4));
            f16x8 bfB = cvt8(*(const float4*)(wb), *(const float4*)(wb + 4));
            accA[ct] = __builtin_amdgcn_mfma_f32_16x16x32_f16(af, bfA, accA[ct], 0, 0, 0);
            accB[ct] = __builtin_amdgcn_mfma_f32_16x16x32_f16(af, bfB, accB[ct], 0, 0, 0);
        }
    }
#pragma unroll
    for (int ct = 0; ct < 4; ++ct) {
#pragma unroll
        for (int i = 0; i < 4; ++i) {
            int row = r0 + kg * 4 + i;
            if (row < NN) {
                store_conv<TA>(&outA[(size_t)row * 64 + ct * 16 + rl], accA[ct][i]);
                store_conv<TB>(&outB[(size_t)row * 64 + ct * 16 + rl], accB[ct][i]);
            }
        }
    }
}

// ---------------- fused agg + dual MFMA GEMM (layers 2,3; K=64) ----------------
// 128 threads = 2 waves, 32 nodes/block. Agg: 16 groups of 8 lanes (uint4 = 8
// halves/lane), 8-deep gather unroll (8 loads in flight). GEMM: wave = 16 rows.
template <typename TA, typename TB>
__global__ __launch_bounds__(128) void fused_agg_gemm(
    const __half* __restrict__ p, const float* __restrict__ selfp,
    const float* __restrict__ bias, const int* __restrict__ row_start,
    const int* __restrict__ csr_src,
    const float* __restrict__ Wa, const float* __restrict__ Wb,
    TA* __restrict__ outA, TB* __restrict__ outB) {
    __shared__ float Xs[32][68];  // padded rows (272B, 16B-aligned)
    int t = threadIdx.x;
    int rbase = blockIdx.x * 32;
    {
        int grp = t >> 3, sub = t & 7;   // 16 groups of 8 lanes
        const uint4* p4 = (const uint4*)p;
#pragma unroll
        for (int pass = 0; pass < 2; ++pass) {
            int nl = pass * 16 + grp;
            int node = rbase + nl;
            float acc[8] = {0.f, 0.f, 0.f, 0.f, 0.f, 0.f, 0.f, 0.f};
            float4 rA = make_float4(0.f, 0.f, 0.f, 0.f);
            float4 rB = make_float4(0.f, 0.f, 0.f, 0.f);
            if (node < NN) {
                int s0 = row_start[node], s1 = row_start[node + 1];
                int e = s0;
                for (; e + 8 <= s1; e += 8) {
                    int idx[8];
#pragma unroll
                    for (int j = 0; j < 8; ++j) idx[j] = csr_src[e + j];
                    uint4 g[8];
#pragma unroll
                    for (int j = 0; j < 8; ++j) g[j] = p4[(size_t)idx[j] * 8 + sub];
#pragma unroll
                    for (int j = 0; j < 8; ++j) {
                        float2 f0 = u2f2(g[j].x), f1 = u2f2(g[j].y);
                        float2 f2 = u2f2(g[j].z), f3 = u2f2(g[j].w);
                        acc[0] += f0.x; acc[1] += f0.y; acc[2] += f1.x; acc[3] += f1.y;
                        acc[4] += f2.x; acc[5] += f2.y; acc[6] += f3.x; acc[7] += f3.y;
                    }
                }
                for (; e + 4 <= s1; e += 4) {
                    int idx[4];
#pragma unroll
                    for (int j = 0; j < 4; ++j) idx[j] = csr_src[e + j];
                    uint4 g[4];
#pragma unroll
                    for (int j = 0; j < 4; ++j) g[j] = p4[(size_t)idx[j] * 8 + sub];
#pragma unroll
                    for (int j = 0; j < 4; ++j) {
                        float2 f0 = u2f2(g[j].x), f1 = u2f2(g[j].y);
                        float2 f2 = u2f2(g[j].z), f3 = u2f2(g[j].w);
                        acc[0] += f0.x; acc[1] += f0.y; acc[2] += f1.x; acc[3] += f1.y;
                        acc[4] += f2.x; acc[5] += f2.y; acc[6] += f3.x; acc[7] += f3.y;
                    }
                }
                for (; e < s1; ++e) {
                    uint4 g = p4[(size_t)csr_src[e] * 8 + sub];
                    float2 f0 = u2f2(g.x), f1 = u2f2(g.y);
                    float2 f2 = u2f2(g.z), f3 = u2f2(g.w);
                    acc[0] += f0.x; acc[1] += f0.y; acc[2] += f1.x; acc[3] += f1.y;
                    acc[4] += f2.x; acc[5] += f2.y; acc[6] += f3.x; acc[7] += f3.y;
                }
                float inv = 1.f / fmaxf((float)(s1 - s0), 1.f);
                const float4* self4 = (const float4*)selfp;
                float4 sA = self4[(size_t)node * 16 + sub * 2];
                float4 sB = self4[(size_t)node * 16 + sub * 2 + 1];
                float4 bA = ((const float4*)bias)[sub * 2];
                float4 bB = ((const float4*)bias)[sub * 2 + 1];
                rA.x = fmaxf(fmaf(acc[0], inv, bA.x + sA.x), 0.f);
                rA.y = fmaxf(fmaf(acc[1], inv, bA.y + sA.y), 0.f);
                rA.z = fmaxf(fmaf(acc[2], inv, bA.z + sA.z), 0.f);
                rA.w = fmaxf(fmaf(acc[3], inv, bA.w + sA.w), 0.f);
                rB.x = fmaxf(fmaf(acc[4], inv, bB.x + sB.x), 0.f);
                rB.y = fmaxf(fmaf(acc[5], inv, bB.y + sB.y), 0.f);
                rB.z = fmaxf(fmaf(acc[6], inv, bB.z + sB.z), 0.f);
                rB.w = fmaxf(fmaf(acc[7], inv, bB.w + sB.w), 0.f);
            }
            *(float4*)&Xs[nl][sub * 8] = rA;
            *(float4*)&Xs[nl][sub * 8 + 4] = rB;
        }
    }
    __syncthreads();
    int lane = t & 63, w = t >> 6;
    int rl = lane & 15, kg = lane >> 4;
    int lrow = w * 16 + rl;
    const float* warow = Wa + (size_t)rl * 64 + kg * 8;
    const float* wbrow = Wb + (size_t)rl * 64 + kg * 8;
    f32x4 accA[4], accB[4];
#pragma unroll
    for (int ct = 0; ct < 4; ++ct) {
        accA[ct] = (f32x4){0.f, 0.f, 0.f, 0.f};
        accB[ct] = (f32x4){0.f, 0.f, 0.f, 0.f};
    }
#pragma unroll
    for (int ks = 0; ks < 64; ks += 32) {
        float4 a0 = *(const float4*)&Xs[lrow][kg * 8 + ks];
        float4 a1 = *(const float4*)&Xs[lrow][kg * 8 + ks + 4];
        f16x8 af = cvt8(a0, a1);
#pragma unroll
        for (int ct = 0; ct < 4; ++ct) {
            const float* wa = warow + (size_t)ct * 16 * 64 + ks;
            const float* wb = wbrow + (size_t)ct * 16 * 64 + ks;
            f16x8 bfA = cvt8(*(const float4*)(wa), *(const float4*)(wa + 4));
            f16x8 bfB = cvt8(*(const float4*)(wb), *(const float4*)(wb + 4));
            accA[ct] = __builtin_amdgcn_mfma_f32_16x16x32_f16(af, bfA, accA[ct], 0, 0, 0);
            accB[ct] = __builtin_amdgcn_mfma_f32_16x16x32_f16(af, bfB, accB[ct], 0, 0, 0);
        }
    }
    int r0 = rbase + w * 16;
#pragma unroll
    for (int ct = 0; ct < 4; ++ct) {
#pragma unroll
        for (int i = 0; i < 4; ++i) {
            int row = r0 + kg * 4 + i;
            if (row < NN) {
                store_conv<TA>(&outA[(size_t)row * 64 + ct * 16 + rl], accA[ct][i]);
                store_conv<TB>(&outB[(size_t)row * 64 + ct * 16 + rl], accB[ct][i]);
            }
        }
    }
}

// ---------------- query head: out = relu(A[u]+B[v]+t*wt+bm1) . Wm2 + bm2 ----------------
// 8 lanes per query (uint4 = 8 halves/lane); grid-stride, constants hoisted.
__global__ __launch_bounds__(256) void query_kernel(
    const int* __restrict__ uv, const float* __restrict__ tf,
    const __half* __restrict__ A, const __half* __restrict__ B,
    const float* __restrict__ wt, const float* __restrict__ bm1,
    const float* __restrict__ Wm2, const float* __restrict__ bm2,
    float* __restrict__ out) {
    int sub = threadIdx.x & 7;
    int gidx = (blockIdx.x * 256 + threadIdx.x) >> 3;
    int ngroups = (gridDim.x * 256) >> 3;
    const uint4* A4 = (const uint4*)A;
    const uint4* B4 = (const uint4*)B;
    const int2* uv2 = (const int2*)uv;
    float4 wtA = ((const float4*)wt)[sub * 2],  wtB = ((const float4*)wt)[sub * 2 + 1];
    float4 bmA = ((const float4*)bm1)[sub * 2], bmB = ((const float4*)bm1)[sub * 2 + 1];
    float4 wmA = ((const float4*)Wm2)[sub * 2], wmB = ((const float4*)Wm2)[sub * 2 + 1];
    float bm2s = bm2[0];
#pragma unroll 2
    for (int q = gidx; q < NQ; q += ngroups) {
        int2 uvq = uv2[q];
        float t = tf[q];
        uint4 au = A4[(size_t)uvq.x * 8 + sub];
        uint4 bv = B4[(size_t)uvq.y * 8 + sub];
        float2 a0 = u2f2(au.x), a1 = u2f2(au.y), a2 = u2f2(au.z), a3 = u2f2(au.w);
        float2 b0 = u2f2(bv.x), b1 = u2f2(bv.y), b2 = u2f2(bv.z), b3 = u2f2(bv.w);
        float s =
            fmaxf(a0.x + b0.x + t * wtA.x + bmA.x, 0.f) * wmA.x +
            fmaxf(a0.y + b0.y + t * wtA.y + bmA.y, 0.f) * wmA.y +
            fmaxf(a1.x + b1.x + t * wtA.z + bmA.z, 0.f) * wmA.z +
            fmaxf(a1.y + b1.y + t * wtA.w + bmA.w, 0.f) * wmA.w +
            fmaxf(a2.x + b2.x + t * wtB.x + bmB.x, 0.f) * wmB.x +
            fmaxf(a2.y + b2.y + t * wtB.y + bmB.y, 0.f) * wmB.y +
            fmaxf(a3.x + b3.x + t * wtB.z + bmB.z, 0.f) * wmB.z +
            fmaxf(a3.y + b3.y + t * wtB.w + bmB.w, 0.f) * wmB.w;
        s += __shfl_down(s, 4, 8);
        s += __shfl_down(s, 2, 8);
        s += __shfl_down(s, 1, 8);
        if (sub == 0) out[q] = s + bm2s;
    }
}

extern "C" void kernel_launch(void* const* d_in, const int* in_sizes, int n_in,
                              void* d_out, int out_size, void* d_ws, size_t ws_size,
                              hipStream_t stream) {
    const float* x   = (const float*)d_in[0];
    const int*   ei  = (const int*)d_in[1];
    const int*   uv  = (const int*)d_in[2];
    const float* tf  = (const float*)d_in[3];
    const float* W1l = (const float*)d_in[4];
    const float* b1  = (const float*)d_in[5];
    const float* W1r = (const float*)d_in[6];
    const float* W2l = (const float*)d_in[7];
    const float* b2  = (const float*)d_in[8];
    const float* W2r = (const float*)d_in[9];
    const float* Wm1 = (const float*)d_in[10];
    const float* bm1 = (const float*)d_in[11];
    const float* Wm2 = (const float*)d_in[12];
    const float* bm2 = (const float*)d_in[13];
    float* out = (float*)d_out;

    char* ws = (char*)d_ws;
    size_t off = 0;
    auto take = [&](size_t bytes) -> void* {
        void* p = ws + off;
        off = (off + bytes + 255) & ~(size_t)255;
        return p;
    };
    int* row_start = (int*)take((NN + 1) * sizeof(int));
    int* csr_src   = (int*)take((size_t)NE * sizeof(int));
    unsigned* tmp  = (unsigned*)take((size_t)NE * sizeof(unsigned));
    int* hist      = (int*)take((size_t)NBLK_S * NBUCKET * sizeof(int));
    int* total     = (int*)take((NBUCKET + 1) * sizeof(int));
    int* bucket_base = (int*)take((NBUCKET + 1) * sizeof(int));
    float* WmA = (float*)take(64 * 64 * sizeof(float));
    float* WmB = (float*)take(64 * 64 * sizeof(float));
    float* wt  = (float*)take(64 * sizeof(float));
    __half* bufA = (__half*)take((size_t)NN * 64 * sizeof(__half));  // p1 / A
    __half* bufC = (__half*)take((size_t)NN * 64 * sizeof(__half));  // p2
    __half* bufE = (__half*)take((size_t)NN * 64 * sizeof(__half));  // B
    float* bufB = (float*)take((size_t)NN * 64 * sizeof(float));     // s1
    float* bufD = (float*)take((size_t)NN * 64 * sizeof(float));     // s2
    (void)in_sizes; (void)n_in; (void)out_size; (void)ws_size;

    const int* esrc = ei;
    const int* edst = ei + NE;

    // CSR build: hist -> totals -> scan(+Wm1 prep) -> offsets -> scatter -> fused fill
    hist_kernel<<<NBLK_S, 256, 0, stream>>>(edst, hist);
    scanA_kernel<<<(NBUCKET + 3) / 4, 256, 0, stream>>>(hist, total);
    scanB_prep_kernel<<<2, 512, 0, stream>>>(total, bucket_base, Wm1, WmA, WmB, wt);
    scanC_kernel<<<(NBUCKET + 3) / 4, 256, 0, stream>>>(hist, bucket_base);
    scatter_kernel<<<NBLK_S, 256, 0, stream>>>(esrc, edst, hist, tmp);
    csr_fill_fused<<<NBUCKET, 256, 0, stream>>>(bucket_base, tmp, csr_src, row_start);

    // Layer 1: p1 = x@W1l.T (fp16 bufA), s1 = x@W1r.T (f32 bufB)
    dual_gemm_mfma<128, __half, float><<<(NN + 63) / 64, 256, 0, stream>>>(x, W1l, W1r, bufA, bufB);
    // Layer 2 fused: h1 = relu(mean(p1)+b1+s1); p2 = h1@W2l.T (bufC), s2 = h1@W2r.T (bufD)
    fused_agg_gemm<__half, float><<<(NN + 31) / 32, 128, 0, stream>>>(
        bufA, bufB, b1, row_start, csr_src, W2l, W2r, bufC, bufD);
    // Layer 3 fused: h2 = relu(mean(p2)+b2+s2); A = h2@WmA.T (bufA), B = h2@WmB.T (bufE)
    fused_agg_gemm<__half, __half><<<(NN + 31) / 32, 128, 0, stream>>>(
        bufC, bufD, b2, row_start, csr_src, WmA, WmB, bufA, bufE);
    // Per-query head
    query_kernel<<<2048, 256, 0, stream>>>(uv, tf, bufA, bufE, wt, bm1, Wm2, bm2, out);
}